// Round 10
// baseline (1429.147 us; speedup 1.0000x reference)
//
#include <hip/hip_runtime.h>
#include <cstddef>

#define N_NODES 20000
#define N_EDGES 320000
#define IN_CH   64
#define HID     512
#define G4      2048
#define BN_EPS  1e-5f
// gate order in gates buffer / weight rows: [f | g | i | o]
#define F_OFF   0
#define G_OFF   512
#define I_OFF   1024
#define O_OFF   1536

typedef __attribute__((ext_vector_type(8))) __bf16 bf16x8;
typedef __attribute__((ext_vector_type(4))) float f32x4;

__device__ __forceinline__ float sigmoidf_(float x) {
  return 1.0f / (1.0f + expf(-x));
}

// fp32 -> bf16 (RNE)
__device__ __forceinline__ unsigned short f2b(float f) {
  unsigned int u = __float_as_uint(f);
  u += 0x7FFFu + ((u >> 16) & 1u);
  return (unsigned short)(u >> 16);
}
__device__ __forceinline__ float b2f(unsigned short u) {
  return __uint_as_float(((unsigned int)u) << 16);
}

__device__ __forceinline__ void gld_lds16(const unsigned short* g, unsigned short* l) {
  __builtin_amdgcn_global_load_lds(
      (const __attribute__((address_space(1))) unsigned int*)(const void*)g,
      (__attribute__((address_space(3))) unsigned int*)(void*)l, 16, 0, 0);
}

// ---------------- zero fill ----------------
__global__ __launch_bounds__(256) void zero_k(float* __restrict__ p, size_t n) {
  size_t i = ((size_t)blockIdx.x * 256 + threadIdx.x) * 4;
  if (i + 3 < n) {
    *(float4*)&p[i] = make_float4(0.f, 0.f, 0.f, 0.f);
  } else {
    for (; i < n; i++) p[i] = 0.f;
  }
}

// ---------------- f32 -> bf16 ----------------
__global__ __launch_bounds__(256) void cvt_k(const float* __restrict__ in,
                                             unsigned short* __restrict__ out, size_t n) {
  size_t i = ((size_t)blockIdx.x * 256 + threadIdx.x) * 4;
  if (i + 3 < n) {
    const float4 v = *(const float4*)&in[i];
    ushort4 o; o.x = f2b(v.x); o.y = f2b(v.y); o.z = f2b(v.z); o.w = f2b(v.w);
    *(ushort4*)&out[i] = o;
  } else {
    for (; i < n; i++) out[i] = f2b(in[i]);
  }
}

// ---------------- copy bf16 rows into stride-ldo buffer ----------------
__global__ __launch_bounds__(256) void cpy16_k(const unsigned short* __restrict__ in,
                                               unsigned short* __restrict__ out,
                                               int rows, int ldo) {
  size_t gid = (size_t)blockIdx.x * 256 + threadIdx.x;
  size_t idx = gid * 4;
  if (idx >= (size_t)rows * HID) return;
  int row = (int)(idx >> 9);
  int col = (int)(idx & (HID - 1));
  *(ushort4*)&out[(size_t)row * ldo + col] = *(const ushort4*)&in[idx];
}

// ---------------- transpose + cvt: Wt[n*ldo + k] = bf16(W[k*ldw + n]) ----------------
__global__ void tcvt_k(const float* __restrict__ W, unsigned short* __restrict__ Wt,
                       int K, int NC, int ldw, int ldo) {
  __shared__ float tile[32][33];
  const int n0 = blockIdx.x * 32, k0 = blockIdx.y * 32;
  const int tx = threadIdx.x, ty = threadIdx.y;  // 32 x 8
  #pragma unroll
  for (int i = 0; i < 32; i += 8) {
    int k = k0 + ty + i, n = n0 + tx;
    tile[ty + i][tx] = (k < K && n < NC) ? W[(size_t)k * ldw + n] : 0.f;
  }
  __syncthreads();
  #pragma unroll
  for (int i = 0; i < 32; i += 8) {
    int n = n0 + ty + i, k = k0 + tx;
    if (n < NC && k < K) Wt[(size_t)n * ldo + k] = f2b(tile[tx][ty + i]);
  }
}

// ---------------- CSR build ----------------
__global__ __launch_bounds__(256) void hist_k(const int* __restrict__ dst,
                                              int* __restrict__ counts) {
  int e = blockIdx.x * 256 + threadIdx.x;
  if (e < N_EDGES) atomicAdd(&counts[dst[e]], 1);
}

__global__ __launch_bounds__(1024) void scan_k(const int* __restrict__ counts,
                                               int* __restrict__ offsets,
                                               int* __restrict__ pos, int n) {
  __shared__ int tmp[1024];
  __shared__ int carry_s;
  const int tid = threadIdx.x;
  if (tid == 0) carry_s = 0;
  __syncthreads();
  for (int base = 0; base < n; base += 1024) {
    int i = base + tid;
    int v = (i < n) ? counts[i] : 0;
    tmp[tid] = v;
    __syncthreads();
    #pragma unroll
    for (int off = 1; off < 1024; off <<= 1) {
      int t = (tid >= off) ? tmp[tid - off] : 0;
      __syncthreads();
      tmp[tid] += t;
      __syncthreads();
    }
    if (i < n) {
      int excl = carry_s + tmp[tid] - v;
      offsets[i] = excl;
      pos[i] = excl;
    }
    __syncthreads();
    if (tid == 1023) carry_s += tmp[1023];
    __syncthreads();
  }
  if (tid == 0) offsets[n] = carry_s;
}

__global__ __launch_bounds__(256) void fill_k(
    const int* __restrict__ src, const int* __restrict__ dst,
    const float* __restrict__ ew, int* __restrict__ pos,
    int* __restrict__ s_s, float* __restrict__ w_s) {
  int e = blockIdx.x * 256 + threadIdx.x;
  if (e >= N_EDGES) return;
  int p = atomicAdd(&pos[dst[e]], 1);
  s_s[p] = src[e];
  w_s[p] = ew[e];
}

// ---------------- gather + fused BN stats ----------------
// 16 nodes per block, 256 thr: half = t>>7 handles 8 nodes, cg = t&127 owns 4 cols.
// Per-thread running sum/sumsq over its nodes -> LDS reduce -> block atomics.
__global__ __launch_bounds__(256) void gather_k(
    const unsigned short* __restrict__ XW, const int* __restrict__ offsets,
    const int* __restrict__ s_s, const float* __restrict__ w_s,
    float* __restrict__ H, float* __restrict__ stats) {
  const int half = threadIdx.x >> 7;
  const int cg   = threadIdx.x & 127;
  const int c4   = cg * 4;
  const int n0   = blockIdx.x * 16 + half * 8;
  float4 s1 = make_float4(0.f, 0.f, 0.f, 0.f);
  float4 s2 = make_float4(0.f, 0.f, 0.f, 0.f);
  for (int k = 0; k < 8; k++) {
    const int n = n0 + k;
    const int beg = offsets[n], end = offsets[n + 1];
    float4 acc = make_float4(0.f, 0.f, 0.f, 0.f);
    for (int i = beg; i < end; i++) {
      const int   s = s_s[i];
      const float w = w_s[i];
      const ushort4 v = *(const ushort4*)&XW[(size_t)s * HID + c4];
      acc.x = fmaf(w, b2f(v.x), acc.x);
      acc.y = fmaf(w, b2f(v.y), acc.y);
      acc.z = fmaf(w, b2f(v.z), acc.z);
      acc.w = fmaf(w, b2f(v.w), acc.w);
    }
    *(float4*)&H[(size_t)n * HID + c4] = acc;
    s1.x += acc.x; s1.y += acc.y; s1.z += acc.z; s1.w += acc.w;
    s2.x = fmaf(acc.x, acc.x, s2.x); s2.y = fmaf(acc.y, acc.y, s2.y);
    s2.z = fmaf(acc.z, acc.z, s2.z); s2.w = fmaf(acc.w, acc.w, s2.w);
  }
  __shared__ float4 sh1[2][128];
  __shared__ float4 sh2[2][128];
  sh1[half][cg] = s1;
  sh2[half][cg] = s2;
  __syncthreads();
  if (half == 0) {
    const float4 o1 = sh1[1][cg], o2 = sh2[1][cg];
    atomicAdd(&stats[c4 + 0], s1.x + o1.x);
    atomicAdd(&stats[c4 + 1], s1.y + o1.y);
    atomicAdd(&stats[c4 + 2], s1.z + o1.z);
    atomicAdd(&stats[c4 + 3], s1.w + o1.w);
    atomicAdd(&stats[HID + c4 + 0], s2.x + o2.x);
    atomicAdd(&stats[HID + c4 + 1], s2.y + o2.y);
    atomicAdd(&stats[HID + c4 + 2], s2.z + o2.z);
    atomicAdd(&stats[HID + c4 + 3], s2.w + o2.w);
  }
}

// ---------------- bf16 MFMA GEMM (templated BN), swizzled LDS + XCD mapping ----
// C(f32) or C16(bf16) [M,NC] (+)= A[M,K](bf16, lda) * Bt[NC,K](bf16)^T (+bias)
// K = B row stride AND loop bound for blocks with col0 < 1024;
// Ksmall = loop bound for col0 >= 1024 (variable-K concat; pass Ksmall=K otherwise).
template<int BN>
__global__ __launch_bounds__(256) void gemm_bf16_k(
    const unsigned short* __restrict__ A, const unsigned short* __restrict__ Bt,
    float* __restrict__ C, unsigned short* __restrict__ C16,
    const float* __restrict__ bias,
    int M, int K, int Ksmall, int lda, int NC, int ldc, int acc, int nrowb, int ncolb)
{
  const int b   = blockIdx.x;
  const int xcd = b & 7;
  const int j   = b >> 3;
  const int col_b = j % ncolb;
  const int row_b = (j / ncolb) * 8 + xcd;
  if (row_b >= nrowb) return;

  constexpr int MI = (BN == 128) ? 4 : 2;
  __shared__ unsigned short As[128 * 32];
  __shared__ unsigned short Bs[BN * 32];
  const int row0 = row_b * 128;
  const int col0 = col_b * BN;
  const int Kthis = (col0 < 1024) ? K : Ksmall;
  const int t    = threadIdx.x;
  const int lane = t & 63;
  const int w    = t >> 6;
  const int wro  = (BN == 128) ? (w >> 1) * 64 : w * 32;
  const int wco  = (BN == 128) ? (w & 1) * 64 : 0;
  const int q    = lane >> 4;
  const int l16  = lane & 15;

  f32x4 accr[MI][4] = {};

  for (int k0 = 0; k0 < Kthis; k0 += 32) {
    #pragma unroll
    for (int i = 0; i < 2; i++) {
      int s  = t + i * 256;
      int r  = s >> 2, cq = s & 3;
      int kq = (cq - (r >> 1)) & 3;
      int gr = row0 + r; if (gr > M - 1) gr = M - 1;
      gld_lds16(A + (size_t)gr * lda + k0 + kq * 8, As + (size_t)s * 8);
    }
    #pragma unroll
    for (int i = 0; i < BN / 64; i++) {
      int s  = t + i * 256;
      int r  = s >> 2, cq = s & 3;
      int kq = (cq - (r >> 1)) & 3;
      gld_lds16(Bt + (size_t)(col0 + r) * K + k0 + kq * 8, Bs + (size_t)s * 8);
    }
    __syncthreads();

    bf16x8 af[MI], bf[4];
    #pragma unroll
    for (int mi = 0; mi < MI; mi++) {
      int r = wro + mi * 16 + l16;
      int qs = (q + (r >> 1)) & 3;
      af[mi] = *(const bf16x8*)&As[r * 32 + qs * 8];
    }
    #pragma unroll
    for (int ni = 0; ni < 4; ni++) {
      int r = wco + ni * 16 + l16;
      int qs = (q + (r >> 1)) & 3;
      bf[ni] = *(const bf16x8*)&Bs[r * 32 + qs * 8];
    }
    #pragma unroll
    for (int mi = 0; mi < MI; mi++)
      #pragma unroll
      for (int ni = 0; ni < 4; ni++)
        accr[mi][ni] = __builtin_amdgcn_mfma_f32_16x16x32_bf16(
            af[mi], bf[ni], accr[mi][ni], 0, 0, 0);
    __syncthreads();
  }

  #pragma unroll
  for (int mi = 0; mi < MI; mi++) {
    #pragma unroll
    for (int ni = 0; ni < 4; ni++) {
      int col = col0 + wco + ni * 16 + l16;
      #pragma unroll
      for (int r = 0; r < 4; r++) {
        int row = row0 + wro + mi * 16 + q * 4 + r;
        if (row < M) {
          float v = accr[mi][ni][r];
          if (C16) {
            C16[(size_t)row * ldc + col] = f2b(v);
          } else {
            float* cp = &C[(size_t)row * ldc + col];
            if (acc)       *cp += v;
            else if (bias) *cp  = v + bias[col];
            else           *cp  = v;
          }
        }
      }
    }
  }
}

// ---------------- BN apply + ReLU -> bf16 ----------------
__global__ __launch_bounds__(256) void bn_apply_k(
    const float* __restrict__ H, const float* __restrict__ stats,
    const float* __restrict__ gamma, const float* __restrict__ beta,
    unsigned short* __restrict__ out, int N)
{
  size_t gid = (size_t)blockIdx.x * 256 + threadIdx.x;
  size_t idx = gid * 4;
  if (idx >= (size_t)N * HID) return;
  int col = (int)(idx & (HID - 1));
  const float4 v = *(const float4*)&H[idx];
  float r[4] = {v.x, v.y, v.z, v.w};
  ushort4 o;
  unsigned short* op = &o.x;
  #pragma unroll
  for (int i = 0; i < 4; i++) {
    int c = col + i;
    float mean = stats[c] * (1.0f / N);
    float var  = stats[HID + c] * (1.0f / N) - mean * mean;
    float scale = gamma[c] / sqrtf(var + BN_EPS);
    float shift = beta[c] - mean * scale;
    op[i] = f2b(fmaxf(fmaf(r[i], scale, shift), 0.0f));
  }
  *(ushort4*)&out[idx] = o;
}

// ---------------- LSTM cell part 1 (gate order f|g|i|o; bias added here) --------
// lb = lstmb layer base in ORIGINAL i,f,g,o order: b_i=lb[0:H], b_f=lb[H:2H],
// b_g=lb[2H:3H].
__global__ __launch_bounds__(256) void cell1_k(
    const float* __restrict__ gates, const float* __restrict__ lb,
    const float* __restrict__ cin,
    float* __restrict__ cout, unsigned short* __restrict__ cout16, int ld16,
    int rows, int hasC)
{
  size_t gid = (size_t)blockIdx.x * 256 + threadIdx.x;
  if (gid >= (size_t)rows * HID) return;
  size_t row = gid >> 9;
  int    col = (int)(gid & (HID - 1));
  const float* g = &gates[row * G4];
  float ig = sigmoidf_(g[I_OFF + col] + lb[col]);
  float gg = tanhf(g[G_OFF + col] + lb[2 * HID + col]);
  float c;
  if (hasC) {
    float fg = sigmoidf_(g[F_OFF + col] + lb[HID + col]);
    c = fg * cin[gid] + ig * gg;
  } else {
    c = ig * gg;
  }
  cout[gid] = c;
  cout16[row * ld16 + col] = f2b(c);
}

// ---------------- LSTM cell part 2 (adds b_o = lb[3H:4H]) ----------------
__global__ __launch_bounds__(256) void cell2_k(
    const float* __restrict__ gates, const float* __restrict__ lb,
    const float* __restrict__ cy,
    float* __restrict__ hy, unsigned short* __restrict__ hy16, int ld16, int rows)
{
  size_t gid = (size_t)blockIdx.x * 256 + threadIdx.x;
  if (gid >= (size_t)rows * HID) return;
  size_t row = gid >> 9;
  int    col = (int)(gid & (HID - 1));
  float og = sigmoidf_(gates[row * G4 + O_OFF + col] + lb[3 * HID + col]);
  float h = og * tanhf(cy[gid]);
  hy[gid] = h;
  if (hy16) hy16[row * ld16 + col] = f2b(h);
}

// ---------------- output projection ----------------
__global__ __launch_bounds__(256) void out_k(
    const float* __restrict__ Hh, const float* __restrict__ W,
    const float* __restrict__ b, float* __restrict__ out, int rows)
{
  int wave = (int)(((size_t)blockIdx.x * 256 + threadIdx.x) >> 6);
  int lane = threadIdx.x & 63;
  if (wave >= rows) return;
  const float* hr = &Hh[(size_t)wave * HID];
  float acc[12] = {};
  for (int k = lane; k < HID; k += 64) {
    float hv = hr[k];
    const float* wr = &W[k * 12];
    #pragma unroll
    for (int p = 0; p < 12; p++) acc[p] = fmaf(hv, wr[p], acc[p]);
  }
  #pragma unroll
  for (int p = 0; p < 12; p++) {
    float v = acc[p];
    #pragma unroll
    for (int off = 32; off > 0; off >>= 1) v += __shfl_down(v, off);
    if (lane == 0) out[(size_t)wave * 12 + p] = v + b[p];
  }
}

extern "C" void kernel_launch(void* const* d_in, const int* in_sizes, int n_in,
                              void* d_out, int out_size, void* d_ws, size_t ws_size,
                              hipStream_t stream) {
  const float* x     = (const float*)d_in[0];
  const int*   ei    = (const int*)d_in[1];
  const float* ew    = (const float*)d_in[2];
  const float* gcn0W = (const float*)d_in[3];
  const float* gcnW  = (const float*)d_in[5];
  const float* gamma = (const float*)d_in[7];
  const float* beta  = (const float*)d_in[8];
  const float* wih   = (const float*)d_in[9];
  const float* whh   = (const float*)d_in[10];
  const float* wch   = (const float*)d_in[11];
  const float* lstmb = (const float*)d_in[12];
  const float* outW  = (const float*)d_in[13];
  const float* outb  = (const float*)d_in[14];
  float* out = (float*)d_out;

  const int* src = ei;
  const int* dst = ei + N_EDGES;

  const int CH = (ws_size >= (size_t)215000000) ? 10000 : 5000;
  const int NCHUNK = N_NODES / CH;

  // -------- workspace layout --------
  const size_t NH = (size_t)N_NODES * HID;
  float* ws = (float*)d_ws;
  float* gates = ws;                                 // CH*2048 fp32
  float* bufH  = gates + (size_t)CH * G4;            // NH fp32
  unsigned short* hbA16 = (unsigned short*)(bufH + NH);
  unsigned short* hbB16 = hbA16 + NH;
  unsigned short* x16   = hbB16 + NH;
  unsigned short* g0t   = x16 + (size_t)N_NODES * IN_CH;
  unsigned short* g1t   = g0t   + 512 * 64;
  unsigned short* g2t   = g1t   + 512 * 512;
  unsigned short* wih0t = g2t   + 512 * 512;             // [2048,512] f|g|i|o rows
  unsigned short* wcat3 = wih0t + (size_t)2048 * 512;    // [2048,1536] fused L1 B
  unsigned short* wch0ot= wcat3 + (size_t)2048 * 1536;   // [512,512]
  unsigned short* wch1ot= wch0ot + 512 * 512;            // [512,512]
  unsigned short* wend  = wch1ot + 512 * 512;
  unsigned short *a16, *tail16;                          // concat [CH,1536]
  if (CH == 5000) {
    a16  = hbB16;
    tail16 = wend;
  } else {
    a16  = wend;
    tail16 = a16 + (size_t)CH * 1536;
  }
  float* stats = (float*)tail16;
  int*   csr   = (int*)(stats + 1024);
  int*   counts  = csr;
  int*   offsets = csr + 20032;
  int*   cpos    = csr + 40064;
  int*   s_s     = csr + 60096;
  float* w_s     = (float*)(csr + 380096);

  float* cbuf = bufH;
  float* hbuf = bufH + (size_t)CH * HID;

  const dim3 blk(256);
  auto gemm128 = [&](const unsigned short* A, const unsigned short* Bt, float* C,
                     unsigned short* C16, const float* bias,
                     int M, int K, int Ksmall, int lda, int NC, int ldc, int acc) {
    int nrowb = (M + 127) / 128;
    int ncolb = NC / 128;
    int nblocks = 8 * ((nrowb + 7) / 8) * ncolb;
    hipLaunchKernelGGL((gemm_bf16_k<128>), dim3(nblocks), blk, 0, stream,
                       A, Bt, C, C16, bias, M, K, Ksmall, lda, NC, ldc, acc, nrowb, ncolb);
  };
  auto gemm64 = [&](const unsigned short* A, const unsigned short* Bt, float* C,
                    unsigned short* C16, const float* bias,
                    int M, int K, int lda, int NC, int ldc, int acc) {
    int nrowb = (M + 127) / 128;
    int ncolb = NC / 64;
    int nblocks = 8 * ((nrowb + 7) / 8) * ncolb;
    hipLaunchKernelGGL((gemm_bf16_k<64>), dim3(nblocks), blk, 0, stream,
                       A, Bt, C, C16, bias, M, K, K, lda, NC, ldc, acc, nrowb, ncolb);
  };
  auto tcvt = [&](const float* W, unsigned short* Wt, int K, int NC, int ldw, int ldo) {
    dim3 grid((NC + 31) / 32, (K + 31) / 32);
    hipLaunchKernelGGL(tcvt_k, grid, dim3(32, 8), 0, stream, W, Wt, K, NC, ldw, ldo);
  };
  auto zero = [&](float* p, size_t n) {
    hipLaunchKernelGGL(zero_k, dim3((unsigned)((n / 4 + 255) / 256)), blk, 0, stream, p, n);
  };

  // -------- weight prep (gate order f|g|i|o) --------
  const float* wih1 = wih + (size_t)HID * G4;
  const float* whh1 = whh + (size_t)HID * G4;
  const float* wch1 = wch + (size_t)HID * 3 * HID;
  tcvt(gcn0W, g0t, IN_CH, HID, HID, IN_CH);
  tcvt(gcnW,                     g1t, HID, HID, HID, HID);
  tcvt(gcnW + (size_t)HID * HID, g2t, HID, HID, HID, HID);
  // layer-0 Wih reordered rows: f,g,i,o  (orig col slices: i=0,f=H,g=2H,o=3H)
  tcvt(wih + HID,     wih0t + (size_t)F_OFF * 512, HID, HID, G4, HID);
  tcvt(wih + 2 * HID, wih0t + (size_t)G_OFF * 512, HID, HID, G4, HID);
  tcvt(wih,           wih0t + (size_t)I_OFF * 512, HID, HID, G4, HID);
  tcvt(wih + 3 * HID, wih0t + (size_t)O_OFF * 512, HID, HID, G4, HID);
  // fused layer-1 B [2048 x 1536]: rows f,g get K=1536 (ih|hh|peephole); i,o K=1024
  tcvt(wih1 + HID,     wcat3 + (size_t)F_OFF * 1536,        HID, HID, G4, 1536);
  tcvt(whh1 + HID,     wcat3 + (size_t)F_OFF * 1536 + 512,  HID, HID, G4, 1536);
  tcvt(wch1 + HID,     wcat3 + (size_t)F_OFF * 1536 + 1024, HID, HID, 3 * HID, 1536);
  tcvt(wih1 + 2 * HID, wcat3 + (size_t)G_OFF * 1536,        HID, HID, G4, 1536);
  tcvt(whh1 + 2 * HID, wcat3 + (size_t)G_OFF * 1536 + 512,  HID, HID, G4, 1536);
  tcvt(wch1,           wcat3 + (size_t)G_OFF * 1536 + 1024, HID, HID, 3 * HID, 1536);
  tcvt(wih1,           wcat3 + (size_t)I_OFF * 1536,        HID, HID, G4, 1536);
  tcvt(whh1,           wcat3 + (size_t)I_OFF * 1536 + 512,  HID, HID, G4, 1536);
  tcvt(wih1 + 3 * HID, wcat3 + (size_t)O_OFF * 1536,        HID, HID, G4, 1536);
  tcvt(whh1 + 3 * HID, wcat3 + (size_t)O_OFF * 1536 + 512,  HID, HID, G4, 1536);
  tcvt(wch + 2 * HID,  wch0ot, HID, HID, 3 * HID, HID);   // Wch0 o-peephole
  tcvt(wch1 + 2 * HID, wch1ot, HID, HID, 3 * HID, HID);   // Wch1 o-peephole
  hipLaunchKernelGGL(cvt_k, dim3((N_NODES * IN_CH / 4 + 255) / 256), blk, 0, stream,
                     x, x16, (size_t)N_NODES * IN_CH);

  // -------- CSR build --------
  const int e_blocks = (N_EDGES + 255) / 256;
  zero((float*)counts, N_NODES);
  hipLaunchKernelGGL(hist_k, dim3(e_blocks), blk, 0, stream, dst, counts);
  hipLaunchKernelGGL(scan_k, dim3(1), dim3(1024), 0, stream, counts, offsets, cpos, N_NODES);
  hipLaunchKernelGGL(fill_k, dim3(e_blocks), blk, 0, stream, src, dst, ew, cpos, s_s, w_s);

  // -------- GCN stack (gather has fused BN-stats) --------
  const unsigned short* gWt[3] = {g0t, g1t, g2t};
  const int             gK[3]  = {IN_CH, HID, HID};
  const unsigned short* gA[3]  = {x16, hbA16, hbB16};
  unsigned short*       gO[3]  = {hbA16, hbB16, hbA16};
  unsigned short*       gXW[3] = {hbB16, hbB16, hbA16};
  for (int l = 0; l < 3; l++) {
    gemm64(gA[l], gWt[l], nullptr, gXW[l], nullptr, N_NODES, gK[l], gK[l], HID, HID, 0);
    zero(stats, 2 * HID);
    hipLaunchKernelGGL(gather_k, dim3(N_NODES / 16), blk, 0, stream,
                       gXW[l], offsets, s_s, w_s, bufH, stats);
    hipLaunchKernelGGL(bn_apply_k, dim3((unsigned)(NH / 4 / 256)), blk, 0, stream,
                       bufH, stats, gamma + l * HID, beta + l * HID, gO[l], N_NODES);
  }
  unsigned short* hfin16 = hbA16;

  // -------- LSTM + output, chunked --------
  for (int ci = 0; ci < NCHUNK; ci++) {
    const int r0 = ci * CH;
    const unsigned short* h_c = hfin16 + (size_t)r0 * HID;
    const int cell_blocks = (int)(((size_t)CH * HID + 255) / 256);
    const int cpy_blocks  = (int)(((size_t)CH * HID / 4 + 255) / 256);

    // a16 row = [ h(0:512) | hy0(512:1024) | c(1024:1536) ]
    hipLaunchKernelGGL(cpy16_k, dim3(cpy_blocks), blk, 0, stream, h_c, a16, CH, 1536);

    // layer 0 (h=c=0): gates = h@Wih0 (bias added in cells)
    gemm128(h_c, wih0t, gates, nullptr, nullptr, CH, HID, HID, HID, G4, G4, 0);
    hipLaunchKernelGGL(cell1_k, dim3(cell_blocks), blk, 0, stream,
                       gates, lstmb, (const float*)nullptr, cbuf, a16 + 1024, 1536, CH, 0);
    // o peephole L0: gates[:,O] += c0 @ Wch0_o
    gemm64(a16 + 1024, wch0ot, gates + O_OFF, nullptr, nullptr,
           CH, HID, 1536, HID, G4, 1);
    hipLaunchKernelGGL(cell2_k, dim3(cell_blocks), blk, 0, stream,
                       gates, lstmb, cbuf, hbuf, a16 + 512, 1536, CH);

    // layer 1 fused: gates = [h|hy0|c0] @ wcat3 ; f,g cols K=1536, i,o cols K=1024
    gemm128(a16, wcat3, gates, nullptr, nullptr, CH, 1536, 1024, 1536, G4, G4, 0);
    hipLaunchKernelGGL(cell1_k, dim3(cell_blocks), blk, 0, stream,
                       gates, lstmb + G4, cbuf, cbuf, a16 + 1024, 1536, CH, 1);
    // o peephole L1: gates[:,O] += c1 @ Wch1_o
    gemm64(a16 + 1024, wch1ot, gates + O_OFF, nullptr, nullptr,
           CH, HID, 1536, HID, G4, 1);
    hipLaunchKernelGGL(cell2_k, dim3(cell_blocks), blk, 0, stream,
                       gates, lstmb + G4, cbuf, hbuf, (unsigned short*)nullptr, 0, CH);

    hipLaunchKernelGGL(out_k, dim3((CH * 64 + 255) / 256), blk, 0, stream,
                       hbuf, outW, outb, out + (size_t)r0 * 12, CH);
  }
}

// Round 11
// 1068.057 us; speedup vs baseline: 1.3381x; 1.3381x over previous
//
#include <hip/hip_runtime.h>
#include <cstddef>

#define N_NODES 20000
#define N_EDGES 320000
#define IN_CH   64
#define HID     512
#define G4      2048
#define BN_EPS  1e-5f
// gate order in gates buffer / weight rows: [f | g | i | o]
#define F_OFF   0
#define G_OFF   512
#define I_OFF   1024
#define O_OFF   1536

typedef __attribute__((ext_vector_type(8))) __bf16 bf16x8;
typedef __attribute__((ext_vector_type(4))) float f32x4;

__device__ __forceinline__ float sigmoidf_(float x) {
  return 1.0f / (1.0f + expf(-x));
}

// fp32 -> bf16 (RNE)
__device__ __forceinline__ unsigned short f2b(float f) {
  unsigned int u = __float_as_uint(f);
  u += 0x7FFFu + ((u >> 16) & 1u);
  return (unsigned short)(u >> 16);
}
__device__ __forceinline__ float b2f(unsigned short u) {
  return __uint_as_float(((unsigned int)u) << 16);
}

__device__ __forceinline__ void gld_lds16(const unsigned short* g, unsigned short* l) {
  __builtin_amdgcn_global_load_lds(
      (const __attribute__((address_space(1))) unsigned int*)(const void*)g,
      (__attribute__((address_space(3))) unsigned int*)(void*)l, 16, 0, 0);
}

// ---------------- zero fill ----------------
__global__ __launch_bounds__(256) void zero_k(float* __restrict__ p, size_t n) {
  size_t i = ((size_t)blockIdx.x * 256 + threadIdx.x) * 4;
  if (i + 3 < n) {
    *(float4*)&p[i] = make_float4(0.f, 0.f, 0.f, 0.f);
  } else {
    for (; i < n; i++) p[i] = 0.f;
  }
}

// ---------------- f32 -> bf16 ----------------
__global__ __launch_bounds__(256) void cvt_k(const float* __restrict__ in,
                                             unsigned short* __restrict__ out, size_t n) {
  size_t i = ((size_t)blockIdx.x * 256 + threadIdx.x) * 4;
  if (i + 3 < n) {
    const float4 v = *(const float4*)&in[i];
    ushort4 o; o.x = f2b(v.x); o.y = f2b(v.y); o.z = f2b(v.z); o.w = f2b(v.w);
    *(ushort4*)&out[i] = o;
  } else {
    for (; i < n; i++) out[i] = f2b(in[i]);
  }
}

// ---------------- copy bf16 rows into stride-ldo buffer ----------------
__global__ __launch_bounds__(256) void cpy16_k(const unsigned short* __restrict__ in,
                                               unsigned short* __restrict__ out,
                                               int rows, int ldo) {
  size_t gid = (size_t)blockIdx.x * 256 + threadIdx.x;
  size_t idx = gid * 4;
  if (idx >= (size_t)rows * HID) return;
  int row = (int)(idx >> 9);
  int col = (int)(idx & (HID - 1));
  *(ushort4*)&out[(size_t)row * ldo + col] = *(const ushort4*)&in[idx];
}

// ---------------- transpose + cvt: Wt[n*ldo + k] = bf16(W[k*ldw + n]) ----------------
__global__ void tcvt_k(const float* __restrict__ W, unsigned short* __restrict__ Wt,
                       int K, int NC, int ldw, int ldo) {
  __shared__ float tile[32][33];
  const int n0 = blockIdx.x * 32, k0 = blockIdx.y * 32;
  const int tx = threadIdx.x, ty = threadIdx.y;  // 32 x 8
  #pragma unroll
  for (int i = 0; i < 32; i += 8) {
    int k = k0 + ty + i, n = n0 + tx;
    tile[ty + i][tx] = (k < K && n < NC) ? W[(size_t)k * ldw + n] : 0.f;
  }
  __syncthreads();
  #pragma unroll
  for (int i = 0; i < 32; i += 8) {
    int n = n0 + ty + i, k = k0 + tx;
    if (n < NC && k < K) Wt[(size_t)n * ldo + k] = f2b(tile[tx][ty + i]);
  }
}

// ---------------- CSR build ----------------
__global__ __launch_bounds__(256) void hist_k(const int* __restrict__ dst,
                                              int* __restrict__ counts) {
  int e = blockIdx.x * 256 + threadIdx.x;
  if (e < N_EDGES) atomicAdd(&counts[dst[e]], 1);
}

__global__ __launch_bounds__(1024) void scan_k(const int* __restrict__ counts,
                                               int* __restrict__ offsets,
                                               int* __restrict__ pos, int n) {
  __shared__ int tmp[1024];
  __shared__ int carry_s;
  const int tid = threadIdx.x;
  if (tid == 0) carry_s = 0;
  __syncthreads();
  for (int base = 0; base < n; base += 1024) {
    int i = base + tid;
    int v = (i < n) ? counts[i] : 0;
    tmp[tid] = v;
    __syncthreads();
    #pragma unroll
    for (int off = 1; off < 1024; off <<= 1) {
      int t = (tid >= off) ? tmp[tid - off] : 0;
      __syncthreads();
      tmp[tid] += t;
      __syncthreads();
    }
    if (i < n) {
      int excl = carry_s + tmp[tid] - v;
      offsets[i] = excl;
      pos[i] = excl;
    }
    __syncthreads();
    if (tid == 1023) carry_s += tmp[1023];
    __syncthreads();
  }
  if (tid == 0) offsets[n] = carry_s;
}

__global__ __launch_bounds__(256) void fill_k(
    const int* __restrict__ src, const int* __restrict__ dst,
    const float* __restrict__ ew, int* __restrict__ pos,
    int* __restrict__ s_s, float* __restrict__ w_s) {
  int e = blockIdx.x * 256 + threadIdx.x;
  if (e >= N_EDGES) return;
  int p = atomicAdd(&pos[dst[e]], 1);
  s_s[p] = src[e];
  w_s[p] = ew[e];
}

// ---------------- aggregation gather (bf16 XW, fp32 accumulate) ----------------
// one block (128 thr) per node; thread t owns 4 cols. 20000 blocks -> latency-hiding
// via massive TLP (R10's 16-node/block fusion was latency-bound at 1250 blocks).
__global__ __launch_bounds__(128) void gather_k(
    const unsigned short* __restrict__ XW, const int* __restrict__ offsets,
    const int* __restrict__ s_s, const float* __restrict__ w_s,
    float* __restrict__ H) {
  const int n = blockIdx.x;
  const int t = threadIdx.x;
  const int beg = offsets[n], end = offsets[n + 1];
  float4 acc = make_float4(0.f, 0.f, 0.f, 0.f);
  for (int i = beg; i < end; i++) {
    const int   s = s_s[i];
    const float w = w_s[i];
    const ushort4 v = *(const ushort4*)&XW[(size_t)s * HID + t * 4];
    acc.x = fmaf(w, b2f(v.x), acc.x);
    acc.y = fmaf(w, b2f(v.y), acc.y);
    acc.z = fmaf(w, b2f(v.z), acc.z);
    acc.w = fmaf(w, b2f(v.w), acc.w);
  }
  *(float4*)&H[(size_t)n * HID + t * 4] = acc;
}

// ---------------- BN stats (separate pass; 512 blocks, row-strided) ----------------
__global__ __launch_bounds__(256) void bn_stats_k(
    const float* __restrict__ H, float* __restrict__ stats, int N)
{
  const int tx = threadIdx.x & 63;
  const int ty = threadIdx.x >> 6;
  const int col = blockIdx.x * 64 + tx;
  float s1 = 0.f, s2 = 0.f;
  for (int r = blockIdx.y * 4 + ty; r < N; r += gridDim.y * 4) {
    float v = H[(size_t)r * HID + col];
    s1 += v; s2 += v * v;
  }
  __shared__ float red[2][4][64];
  red[0][ty][tx] = s1;
  red[1][ty][tx] = s2;
  __syncthreads();
  if (ty == 0) {
    s1 = red[0][0][tx] + red[0][1][tx] + red[0][2][tx] + red[0][3][tx];
    s2 = red[1][0][tx] + red[1][1][tx] + red[1][2][tx] + red[1][3][tx];
    atomicAdd(&stats[col], s1);
    atomicAdd(&stats[HID + col], s2);
  }
}

// ---------------- bf16 MFMA GEMM (templated BN), swizzled LDS + XCD mapping ----
// C(f32) or C16(bf16) [M,NC] (+)= A[M,K](bf16, lda) * Bt[NC,K](bf16)^T (+bias)
// K = B row stride AND loop bound for blocks with col0 < 1024;
// Ksmall = loop bound for col0 >= 1024 (variable-K concat; pass Ksmall=K otherwise).
template<int BN>
__global__ __launch_bounds__(256) void gemm_bf16_k(
    const unsigned short* __restrict__ A, const unsigned short* __restrict__ Bt,
    float* __restrict__ C, unsigned short* __restrict__ C16,
    const float* __restrict__ bias,
    int M, int K, int Ksmall, int lda, int NC, int ldc, int acc, int nrowb, int ncolb)
{
  const int b   = blockIdx.x;
  const int xcd = b & 7;
  const int j   = b >> 3;
  const int col_b = j % ncolb;
  const int row_b = (j / ncolb) * 8 + xcd;
  if (row_b >= nrowb) return;

  constexpr int MI = (BN == 128) ? 4 : 2;
  __shared__ unsigned short As[128 * 32];
  __shared__ unsigned short Bs[BN * 32];
  const int row0 = row_b * 128;
  const int col0 = col_b * BN;
  const int Kthis = (col0 < 1024) ? K : Ksmall;
  const int t    = threadIdx.x;
  const int lane = t & 63;
  const int w    = t >> 6;
  const int wro  = (BN == 128) ? (w >> 1) * 64 : w * 32;
  const int wco  = (BN == 128) ? (w & 1) * 64 : 0;
  const int q    = lane >> 4;
  const int l16  = lane & 15;

  f32x4 accr[MI][4] = {};

  for (int k0 = 0; k0 < Kthis; k0 += 32) {
    #pragma unroll
    for (int i = 0; i < 2; i++) {
      int s  = t + i * 256;
      int r  = s >> 2, cq = s & 3;
      int kq = (cq - (r >> 1)) & 3;
      int gr = row0 + r; if (gr > M - 1) gr = M - 1;
      gld_lds16(A + (size_t)gr * lda + k0 + kq * 8, As + (size_t)s * 8);
    }
    #pragma unroll
    for (int i = 0; i < BN / 64; i++) {
      int s  = t + i * 256;
      int r  = s >> 2, cq = s & 3;
      int kq = (cq - (r >> 1)) & 3;
      gld_lds16(Bt + (size_t)(col0 + r) * K + k0 + kq * 8, Bs + (size_t)s * 8);
    }
    __syncthreads();

    bf16x8 af[MI], bf[4];
    #pragma unroll
    for (int mi = 0; mi < MI; mi++) {
      int r = wro + mi * 16 + l16;
      int qs = (q + (r >> 1)) & 3;
      af[mi] = *(const bf16x8*)&As[r * 32 + qs * 8];
    }
    #pragma unroll
    for (int ni = 0; ni < 4; ni++) {
      int r = wco + ni * 16 + l16;
      int qs = (q + (r >> 1)) & 3;
      bf[ni] = *(const bf16x8*)&Bs[r * 32 + qs * 8];
    }
    #pragma unroll
    for (int mi = 0; mi < MI; mi++)
      #pragma unroll
      for (int ni = 0; ni < 4; ni++)
        accr[mi][ni] = __builtin_amdgcn_mfma_f32_16x16x32_bf16(
            af[mi], bf[ni], accr[mi][ni], 0, 0, 0);
    __syncthreads();
  }

  #pragma unroll
  for (int mi = 0; mi < MI; mi++) {
    #pragma unroll
    for (int ni = 0; ni < 4; ni++) {
      int col = col0 + wco + ni * 16 + l16;
      #pragma unroll
      for (int r = 0; r < 4; r++) {
        int row = row0 + wro + mi * 16 + q * 4 + r;
        if (row < M) {
          float v = accr[mi][ni][r];
          if (C16) {
            C16[(size_t)row * ldc + col] = f2b(v);
          } else {
            float* cp = &C[(size_t)row * ldc + col];
            if (acc)       *cp += v;
            else if (bias) *cp  = v + bias[col];
            else           *cp  = v;
          }
        }
      }
    }
  }
}

// ---------------- BN apply + ReLU -> bf16 ----------------
__global__ __launch_bounds__(256) void bn_apply_k(
    const float* __restrict__ H, const float* __restrict__ stats,
    const float* __restrict__ gamma, const float* __restrict__ beta,
    unsigned short* __restrict__ out, int N)
{
  size_t gid = (size_t)blockIdx.x * 256 + threadIdx.x;
  size_t idx = gid * 4;
  if (idx >= (size_t)N * HID) return;
  int col = (int)(idx & (HID - 1));
  const float4 v = *(const float4*)&H[idx];
  float r[4] = {v.x, v.y, v.z, v.w};
  ushort4 o;
  unsigned short* op = &o.x;
  #pragma unroll
  for (int i = 0; i < 4; i++) {
    int c = col + i;
    float mean = stats[c] * (1.0f / N);
    float var  = stats[HID + c] * (1.0f / N) - mean * mean;
    float scale = gamma[c] / sqrtf(var + BN_EPS);
    float shift = beta[c] - mean * scale;
    op[i] = f2b(fmaxf(fmaf(r[i], scale, shift), 0.0f));
  }
  *(ushort4*)&out[idx] = o;
}

// ---------------- LSTM cell part 1 (gate order f|g|i|o; bias added here) --------
// lb = lstmb layer base in ORIGINAL i,f,g,o order.
__global__ __launch_bounds__(256) void cell1_k(
    const float* __restrict__ gates, const float* __restrict__ lb,
    const float* __restrict__ cin,
    float* __restrict__ cout, unsigned short* __restrict__ cout16, int ld16,
    int rows, int hasC)
{
  size_t gid = (size_t)blockIdx.x * 256 + threadIdx.x;
  if (gid >= (size_t)rows * HID) return;
  size_t row = gid >> 9;
  int    col = (int)(gid & (HID - 1));
  const float* g = &gates[row * G4];
  float ig = sigmoidf_(g[I_OFF + col] + lb[col]);
  float gg = tanhf(g[G_OFF + col] + lb[2 * HID + col]);
  float c;
  if (hasC) {
    float fg = sigmoidf_(g[F_OFF + col] + lb[HID + col]);
    c = fg * cin[gid] + ig * gg;
  } else {
    c = ig * gg;
  }
  cout[gid] = c;
  cout16[row * ld16 + col] = f2b(c);
}

// ---------------- LSTM cell part 2 (adds b_o = lb[3H:4H]) ----------------
__global__ __launch_bounds__(256) void cell2_k(
    const float* __restrict__ gates, const float* __restrict__ lb,
    const float* __restrict__ cy,
    float* __restrict__ hy, unsigned short* __restrict__ hy16, int ld16, int rows)
{
  size_t gid = (size_t)blockIdx.x * 256 + threadIdx.x;
  if (gid >= (size_t)rows * HID) return;
  size_t row = gid >> 9;
  int    col = (int)(gid & (HID - 1));
  float og = sigmoidf_(gates[row * G4 + O_OFF + col] + lb[3 * HID + col]);
  float h = og * tanhf(cy[gid]);
  hy[gid] = h;
  if (hy16) hy16[row * ld16 + col] = f2b(h);
}

// ---------------- output projection ----------------
__global__ __launch_bounds__(256) void out_k(
    const float* __restrict__ Hh, const float* __restrict__ W,
    const float* __restrict__ b, float* __restrict__ out, int rows)
{
  int wave = (int)(((size_t)blockIdx.x * 256 + threadIdx.x) >> 6);
  int lane = threadIdx.x & 63;
  if (wave >= rows) return;
  const float* hr = &Hh[(size_t)wave * HID];
  float acc[12] = {};
  for (int k = lane; k < HID; k += 64) {
    float hv = hr[k];
    const float* wr = &W[k * 12];
    #pragma unroll
    for (int p = 0; p < 12; p++) acc[p] = fmaf(hv, wr[p], acc[p]);
  }
  #pragma unroll
  for (int p = 0; p < 12; p++) {
    float v = acc[p];
    #pragma unroll
    for (int off = 32; off > 0; off >>= 1) v += __shfl_down(v, off);
    if (lane == 0) out[(size_t)wave * 12 + p] = v + b[p];
  }
}

extern "C" void kernel_launch(void* const* d_in, const int* in_sizes, int n_in,
                              void* d_out, int out_size, void* d_ws, size_t ws_size,
                              hipStream_t stream) {
  const float* x     = (const float*)d_in[0];
  const int*   ei    = (const int*)d_in[1];
  const float* ew    = (const float*)d_in[2];
  const float* gcn0W = (const float*)d_in[3];
  const float* gcnW  = (const float*)d_in[5];
  const float* gamma = (const float*)d_in[7];
  const float* beta  = (const float*)d_in[8];
  const float* wih   = (const float*)d_in[9];
  const float* whh   = (const float*)d_in[10];
  const float* wch   = (const float*)d_in[11];
  const float* lstmb = (const float*)d_in[12];
  const float* outW  = (const float*)d_in[13];
  const float* outb  = (const float*)d_in[14];
  float* out = (float*)d_out;

  const int* src = ei;
  const int* dst = ei + N_EDGES;

  const int CH = (ws_size >= (size_t)215000000) ? 10000 : 5000;
  const int NCHUNK = N_NODES / CH;

  // -------- workspace layout --------
  const size_t NH = (size_t)N_NODES * HID;
  float* ws = (float*)d_ws;
  float* gates = ws;                                 // CH*2048 fp32
  float* bufH  = gates + (size_t)CH * G4;            // NH fp32
  unsigned short* hbA16 = (unsigned short*)(bufH + NH);
  unsigned short* hbB16 = hbA16 + NH;
  unsigned short* x16   = hbB16 + NH;
  unsigned short* g0t   = x16 + (size_t)N_NODES * IN_CH;
  unsigned short* g1t   = g0t   + 512 * 64;
  unsigned short* g2t   = g1t   + 512 * 512;
  unsigned short* wih0t = g2t   + 512 * 512;             // [2048,512] f|g|i|o rows
  unsigned short* wcat3 = wih0t + (size_t)2048 * 512;    // [2048,1536] fused L1 B
  unsigned short* wch0ot= wcat3 + (size_t)2048 * 1536;   // [512,512]
  unsigned short* wch1ot= wch0ot + 512 * 512;            // [512,512]
  unsigned short* wend  = wch1ot + 512 * 512;
  unsigned short *a16, *tail16;                          // concat [CH,1536]
  if (CH == 5000) {
    a16  = hbB16;
    tail16 = wend;
  } else {
    a16  = wend;
    tail16 = a16 + (size_t)CH * 1536;
  }
  float* stats = (float*)tail16;
  int*   csr   = (int*)(stats + 1024);
  int*   counts  = csr;
  int*   offsets = csr + 20032;
  int*   cpos    = csr + 40064;
  int*   s_s     = csr + 60096;
  float* w_s     = (float*)(csr + 380096);

  float* cbuf = bufH;
  float* hbuf = bufH + (size_t)CH * HID;

  const dim3 blk(256);
  auto gemm128 = [&](const unsigned short* A, const unsigned short* Bt, float* C,
                     unsigned short* C16, const float* bias,
                     int M, int K, int Ksmall, int lda, int NC, int ldc, int acc) {
    int nrowb = (M + 127) / 128;
    int ncolb = NC / 128;
    int nblocks = 8 * ((nrowb + 7) / 8) * ncolb;
    hipLaunchKernelGGL((gemm_bf16_k<128>), dim3(nblocks), blk, 0, stream,
                       A, Bt, C, C16, bias, M, K, Ksmall, lda, NC, ldc, acc, nrowb, ncolb);
  };
  auto gemm64 = [&](const unsigned short* A, const unsigned short* Bt, float* C,
                    unsigned short* C16, const float* bias,
                    int M, int K, int lda, int NC, int ldc, int acc) {
    int nrowb = (M + 127) / 128;
    int ncolb = NC / 64;
    int nblocks = 8 * ((nrowb + 7) / 8) * ncolb;
    hipLaunchKernelGGL((gemm_bf16_k<64>), dim3(nblocks), blk, 0, stream,
                       A, Bt, C, C16, bias, M, K, K, lda, NC, ldc, acc, nrowb, ncolb);
  };
  auto tcvt = [&](const float* W, unsigned short* Wt, int K, int NC, int ldw, int ldo) {
    dim3 grid((NC + 31) / 32, (K + 31) / 32);
    hipLaunchKernelGGL(tcvt_k, grid, dim3(32, 8), 0, stream, W, Wt, K, NC, ldw, ldo);
  };
  auto zero = [&](float* p, size_t n) {
    hipLaunchKernelGGL(zero_k, dim3((unsigned)((n / 4 + 255) / 256)), blk, 0, stream, p, n);
  };

  // -------- weight prep (gate order f|g|i|o) --------
  const float* wih1 = wih + (size_t)HID * G4;
  const float* whh1 = whh + (size_t)HID * G4;
  const float* wch1 = wch + (size_t)HID * 3 * HID;
  tcvt(gcn0W, g0t, IN_CH, HID, HID, IN_CH);
  tcvt(gcnW,                     g1t, HID, HID, HID, HID);
  tcvt(gcnW + (size_t)HID * HID, g2t, HID, HID, HID, HID);
  // layer-0 Wih reordered rows: f,g,i,o  (orig col slices: i=0,f=H,g=2H,o=3H)
  tcvt(wih + HID,     wih0t + (size_t)F_OFF * 512, HID, HID, G4, HID);
  tcvt(wih + 2 * HID, wih0t + (size_t)G_OFF * 512, HID, HID, G4, HID);
  tcvt(wih,           wih0t + (size_t)I_OFF * 512, HID, HID, G4, HID);
  tcvt(wih + 3 * HID, wih0t + (size_t)O_OFF * 512, HID, HID, G4, HID);
  // fused layer-1 B [2048 x 1536]: rows f,g get K=1536 (ih|hh|peephole); i,o K=1024
  tcvt(wih1 + HID,     wcat3 + (size_t)F_OFF * 1536,        HID, HID, G4, 1536);
  tcvt(whh1 + HID,     wcat3 + (size_t)F_OFF * 1536 + 512,  HID, HID, G4, 1536);
  tcvt(wch1 + HID,     wcat3 + (size_t)F_OFF * 1536 + 1024, HID, HID, 3 * HID, 1536);
  tcvt(wih1 + 2 * HID, wcat3 + (size_t)G_OFF * 1536,        HID, HID, G4, 1536);
  tcvt(whh1 + 2 * HID, wcat3 + (size_t)G_OFF * 1536 + 512,  HID, HID, G4, 1536);
  tcvt(wch1,           wcat3 + (size_t)G_OFF * 1536 + 1024, HID, HID, 3 * HID, 1536);
  tcvt(wih1,           wcat3 + (size_t)I_OFF * 1536,        HID, HID, G4, 1536);
  tcvt(whh1,           wcat3 + (size_t)I_OFF * 1536 + 512,  HID, HID, G4, 1536);
  tcvt(wih1 + 3 * HID, wcat3 + (size_t)O_OFF * 1536,        HID, HID, G4, 1536);
  tcvt(whh1 + 3 * HID, wcat3 + (size_t)O_OFF * 1536 + 512,  HID, HID, G4, 1536);
  tcvt(wch + 2 * HID,  wch0ot, HID, HID, 3 * HID, HID);   // Wch0 o-peephole
  tcvt(wch1 + 2 * HID, wch1ot, HID, HID, 3 * HID, HID);   // Wch1 o-peephole
  hipLaunchKernelGGL(cvt_k, dim3((N_NODES * IN_CH / 4 + 255) / 256), blk, 0, stream,
                     x, x16, (size_t)N_NODES * IN_CH);

  // -------- CSR build --------
  const int e_blocks = (N_EDGES + 255) / 256;
  zero((float*)counts, N_NODES);
  hipLaunchKernelGGL(hist_k, dim3(e_blocks), blk, 0, stream, dst, counts);
  hipLaunchKernelGGL(scan_k, dim3(1), dim3(1024), 0, stream, counts, offsets, cpos, N_NODES);
  hipLaunchKernelGGL(fill_k, dim3(e_blocks), blk, 0, stream, src, dst, ew, cpos, s_s, w_s);

  // -------- GCN stack --------
  const unsigned short* gWt[3] = {g0t, g1t, g2t};
  const int             gK[3]  = {IN_CH, HID, HID};
  const unsigned short* gA[3]  = {x16, hbA16, hbB16};
  unsigned short*       gO[3]  = {hbA16, hbB16, hbA16};
  unsigned short*       gXW[3] = {hbB16, hbB16, hbA16};
  for (int l = 0; l < 3; l++) {
    gemm64(gA[l], gWt[l], nullptr, gXW[l], nullptr, N_NODES, gK[l], gK[l], HID, HID, 0);
    hipLaunchKernelGGL(gather_k, dim3(N_NODES), dim3(128), 0, stream,
                       gXW[l], offsets, s_s, w_s, bufH);
    zero(stats, 2 * HID);
    hipLaunchKernelGGL(bn_stats_k, dim3(8, 64), blk, 0, stream, bufH, stats, N_NODES);
    hipLaunchKernelGGL(bn_apply_k, dim3((unsigned)(NH / 4 / 256)), blk, 0, stream,
                       bufH, stats, gamma + l * HID, beta + l * HID, gO[l], N_NODES);
  }
  unsigned short* hfin16 = hbA16;

  // -------- LSTM + output, chunked --------
  for (int ci = 0; ci < NCHUNK; ci++) {
    const int r0 = ci * CH;
    const unsigned short* h_c = hfin16 + (size_t)r0 * HID;
    const int cell_blocks = (int)(((size_t)CH * HID + 255) / 256);
    const int cpy_blocks  = (int)(((size_t)CH * HID / 4 + 255) / 256);

    // a16 row = [ h(0:512) | hy0(512:1024) | c(1024:1536) ]
    hipLaunchKernelGGL(cpy16_k, dim3(cpy_blocks), blk, 0, stream, h_c, a16, CH, 1536);

    // layer 0 (h=c=0): gates = h@Wih0 (bias added in cells)
    gemm128(h_c, wih0t, gates, nullptr, nullptr, CH, HID, HID, HID, G4, G4, 0);
    hipLaunchKernelGGL(cell1_k, dim3(cell_blocks), blk, 0, stream,
                       gates, lstmb, (const float*)nullptr, cbuf, a16 + 1024, 1536, CH, 0);
    // o peephole L0: gates[:,O] += c0 @ Wch0_o
    gemm64(a16 + 1024, wch0ot, gates + O_OFF, nullptr, nullptr,
           CH, HID, 1536, HID, G4, 1);
    hipLaunchKernelGGL(cell2_k, dim3(cell_blocks), blk, 0, stream,
                       gates, lstmb, cbuf, hbuf, a16 + 512, 1536, CH);

    // layer 1 fused: gates = [h|hy0|c0] @ wcat3 ; f,g cols K=1536, i,o cols K=1024
    gemm128(a16, wcat3, gates, nullptr, nullptr, CH, 1536, 1024, 1536, G4, G4, 0);
    hipLaunchKernelGGL(cell1_k, dim3(cell_blocks), blk, 0, stream,
                       gates, lstmb + G4, cbuf, cbuf, a16 + 1024, 1536, CH, 1);
    // o peephole L1: gates[:,O] += c1 @ Wch1_o
    gemm64(a16 + 1024, wch1ot, gates + O_OFF, nullptr, nullptr,
           CH, HID, 1536, HID, G4, 1);
    hipLaunchKernelGGL(cell2_k, dim3(cell_blocks), blk, 0, stream,
                       gates, lstmb + G4, cbuf, hbuf, (unsigned short*)nullptr, 0, CH);

    hipLaunchKernelGGL(out_k, dim3((CH * 64 + 255) / 256), blk, 0, stream,
                       hbuf, outW, outb, out + (size_t)r0 * 12, CH);
  }
}

// Round 12
// 1022.949 us; speedup vs baseline: 1.3971x; 1.0441x over previous
//
#include <hip/hip_runtime.h>
#include <cstddef>

#define N_NODES 20000
#define N_EDGES 320000
#define IN_CH   64
#define HID     512
#define G4      2048
#define BN_EPS  1e-5f
// gate order in gates buffer / weight rows: [f | g | i | o]
#define F_OFF   0
#define G_OFF   512
#define I_OFF   1024
#define O_OFF   1536

typedef __attribute__((ext_vector_type(8))) __bf16 bf16x8;
typedef __attribute__((ext_vector_type(4))) float f32x4;

__device__ __forceinline__ float sigmoidf_(float x) {
  return 1.0f / (1.0f + expf(-x));
}

// fp32 -> bf16 (RNE)
__device__ __forceinline__ unsigned short f2b(float f) {
  unsigned int u = __float_as_uint(f);
  u += 0x7FFFu + ((u >> 16) & 1u);
  return (unsigned short)(u >> 16);
}
__device__ __forceinline__ float b2f(unsigned short u) {
  return __uint_as_float(((unsigned int)u) << 16);
}

__device__ __forceinline__ void gld_lds16(const unsigned short* g, unsigned short* l) {
  __builtin_amdgcn_global_load_lds(
      (const __attribute__((address_space(1))) unsigned int*)(const void*)g,
      (__attribute__((address_space(3))) unsigned int*)(void*)l, 16, 0, 0);
}

// ---------------- zero fill ----------------
__global__ __launch_bounds__(256) void zero_k(float* __restrict__ p, size_t n) {
  size_t i = ((size_t)blockIdx.x * 256 + threadIdx.x) * 4;
  if (i + 3 < n) {
    *(float4*)&p[i] = make_float4(0.f, 0.f, 0.f, 0.f);
  } else {
    for (; i < n; i++) p[i] = 0.f;
  }
}

// ---------------- f32 -> bf16 ----------------
__global__ __launch_bounds__(256) void cvt_k(const float* __restrict__ in,
                                             unsigned short* __restrict__ out, size_t n) {
  size_t i = ((size_t)blockIdx.x * 256 + threadIdx.x) * 4;
  if (i + 3 < n) {
    const float4 v = *(const float4*)&in[i];
    ushort4 o; o.x = f2b(v.x); o.y = f2b(v.y); o.z = f2b(v.z); o.w = f2b(v.w);
    *(ushort4*)&out[i] = o;
  } else {
    for (; i < n; i++) out[i] = f2b(in[i]);
  }
}

// ---------------- copy bf16 rows into stride-ldo buffer ----------------
__global__ __launch_bounds__(256) void cpy16_k(const unsigned short* __restrict__ in,
                                               unsigned short* __restrict__ out,
                                               int rows, int ldo) {
  size_t gid = (size_t)blockIdx.x * 256 + threadIdx.x;
  size_t idx = gid * 4;
  if (idx >= (size_t)rows * HID) return;
  int row = (int)(idx >> 9);
  int col = (int)(idx & (HID - 1));
  *(ushort4*)&out[(size_t)row * ldo + col] = *(const ushort4*)&in[idx];
}

// ---------------- transpose + cvt: Wt[n*ldo + k] = bf16(W[k*ldw + n]) ----------------
__global__ void tcvt_k(const float* __restrict__ W, unsigned short* __restrict__ Wt,
                       int K, int NC, int ldw, int ldo) {
  __shared__ float tile[32][33];
  const int n0 = blockIdx.x * 32, k0 = blockIdx.y * 32;
  const int tx = threadIdx.x, ty = threadIdx.y;  // 32 x 8
  #pragma unroll
  for (int i = 0; i < 32; i += 8) {
    int k = k0 + ty + i, n = n0 + tx;
    tile[ty + i][tx] = (k < K && n < NC) ? W[(size_t)k * ldw + n] : 0.f;
  }
  __syncthreads();
  #pragma unroll
  for (int i = 0; i < 32; i += 8) {
    int n = n0 + ty + i, k = k0 + tx;
    if (n < NC && k < K) Wt[(size_t)n * ldo + k] = f2b(tile[tx][ty + i]);
  }
}

// ---------------- CSR build ----------------
__global__ __launch_bounds__(256) void hist_k(const int* __restrict__ dst,
                                              int* __restrict__ counts) {
  int e = blockIdx.x * 256 + threadIdx.x;
  if (e < N_EDGES) atomicAdd(&counts[dst[e]], 1);
}

__global__ __launch_bounds__(1024) void scan_k(const int* __restrict__ counts,
                                               int* __restrict__ offsets,
                                               int* __restrict__ pos, int n) {
  __shared__ int tmp[1024];
  __shared__ int carry_s;
  const int tid = threadIdx.x;
  if (tid == 0) carry_s = 0;
  __syncthreads();
  for (int base = 0; base < n; base += 1024) {
    int i = base + tid;
    int v = (i < n) ? counts[i] : 0;
    tmp[tid] = v;
    __syncthreads();
    #pragma unroll
    for (int off = 1; off < 1024; off <<= 1) {
      int t = (tid >= off) ? tmp[tid - off] : 0;
      __syncthreads();
      tmp[tid] += t;
      __syncthreads();
    }
    if (i < n) {
      int excl = carry_s + tmp[tid] - v;
      offsets[i] = excl;
      pos[i] = excl;
    }
    __syncthreads();
    if (tid == 1023) carry_s += tmp[1023];
    __syncthreads();
  }
  if (tid == 0) offsets[n] = carry_s;
}

__global__ __launch_bounds__(256) void fill_k(
    const int* __restrict__ src, const int* __restrict__ dst,
    const float* __restrict__ ew, int* __restrict__ pos,
    int* __restrict__ s_s, float* __restrict__ w_s) {
  int e = blockIdx.x * 256 + threadIdx.x;
  if (e >= N_EDGES) return;
  int p = atomicAdd(&pos[dst[e]], 1);
  s_s[p] = src[e];
  w_s[p] = ew[e];
}

// ---------------- L0 gather on 64-col input: xg = S·x (linearity) ----------------
// 4 nodes per 64-thr block; 16 lanes per node, lane owns ushort4 (4 cols).
__global__ __launch_bounds__(64) void gather64_k(
    const unsigned short* __restrict__ x16, const int* __restrict__ offsets,
    const int* __restrict__ s_s, const float* __restrict__ w_s,
    unsigned short* __restrict__ xg) {
  const int sub = threadIdx.x >> 4;
  const int cg  = threadIdx.x & 15;
  const int n   = blockIdx.x * 4 + sub;
  const int beg = offsets[n], end = offsets[n + 1];
  float4 acc = make_float4(0.f, 0.f, 0.f, 0.f);
  for (int i = beg; i < end; i++) {
    const int   s = s_s[i];
    const float w = w_s[i];
    const ushort4 v = *(const ushort4*)&x16[(size_t)s * IN_CH + cg * 4];
    acc.x = fmaf(w, b2f(v.x), acc.x);
    acc.y = fmaf(w, b2f(v.y), acc.y);
    acc.z = fmaf(w, b2f(v.z), acc.z);
    acc.w = fmaf(w, b2f(v.w), acc.w);
  }
  ushort4 o; o.x = f2b(acc.x); o.y = f2b(acc.y); o.z = f2b(acc.z); o.w = f2b(acc.w);
  *(ushort4*)&xg[(size_t)n * IN_CH + cg * 4] = o;
}

// ---------------- aggregation gather (bf16 XW -> bf16 H, fp32 accumulate) --------
// one block (128 thr) per node; 20000 blocks for TLP latency hiding.
__global__ __launch_bounds__(128) void gather_k(
    const unsigned short* __restrict__ XW, const int* __restrict__ offsets,
    const int* __restrict__ s_s, const float* __restrict__ w_s,
    unsigned short* __restrict__ H) {
  const int n = blockIdx.x;
  const int t = threadIdx.x;
  const int beg = offsets[n], end = offsets[n + 1];
  float4 acc = make_float4(0.f, 0.f, 0.f, 0.f);
  for (int i = beg; i < end; i++) {
    const int   s = s_s[i];
    const float w = w_s[i];
    const ushort4 v = *(const ushort4*)&XW[(size_t)s * HID + t * 4];
    acc.x = fmaf(w, b2f(v.x), acc.x);
    acc.y = fmaf(w, b2f(v.y), acc.y);
    acc.z = fmaf(w, b2f(v.z), acc.z);
    acc.w = fmaf(w, b2f(v.w), acc.w);
  }
  ushort4 o; o.x = f2b(acc.x); o.y = f2b(acc.y); o.z = f2b(acc.z); o.w = f2b(acc.w);
  *(ushort4*)&H[(size_t)n * HID + t * 4] = o;
}

// ---------------- BN stats over bf16 H ----------------
__global__ __launch_bounds__(256) void bn_stats_k(
    const unsigned short* __restrict__ H, float* __restrict__ stats, int N)
{
  const int tx = threadIdx.x & 63;
  const int ty = threadIdx.x >> 6;
  const int col = blockIdx.x * 64 + tx;
  float s1 = 0.f, s2 = 0.f;
  for (int r = blockIdx.y * 4 + ty; r < N; r += gridDim.y * 4) {
    float v = b2f(H[(size_t)r * HID + col]);
    s1 += v; s2 += v * v;
  }
  __shared__ float red[2][4][64];
  red[0][ty][tx] = s1;
  red[1][ty][tx] = s2;
  __syncthreads();
  if (ty == 0) {
    s1 = red[0][0][tx] + red[0][1][tx] + red[0][2][tx] + red[0][3][tx];
    s2 = red[1][0][tx] + red[1][1][tx] + red[1][2][tx] + red[1][3][tx];
    atomicAdd(&stats[col], s1);
    atomicAdd(&stats[HID + col], s2);
  }
}

// ---------------- BN apply + ReLU: bf16 H -> bf16 h ----------------
__global__ __launch_bounds__(256) void bn_apply_k(
    const unsigned short* __restrict__ H, const float* __restrict__ stats,
    const float* __restrict__ gamma, const float* __restrict__ beta,
    unsigned short* __restrict__ out, int N)
{
  size_t gid = (size_t)blockIdx.x * 256 + threadIdx.x;
  size_t idx = gid * 4;
  if (idx >= (size_t)N * HID) return;
  int col = (int)(idx & (HID - 1));
  const ushort4 v = *(const ushort4*)&H[idx];
  float r[4] = {b2f(v.x), b2f(v.y), b2f(v.z), b2f(v.w)};
  ushort4 o;
  unsigned short* op = &o.x;
  #pragma unroll
  for (int i = 0; i < 4; i++) {
    int c = col + i;
    float mean = stats[c] * (1.0f / N);
    float var  = stats[HID + c] * (1.0f / N) - mean * mean;
    float scale = gamma[c] / sqrtf(var + BN_EPS);
    float shift = beta[c] - mean * scale;
    op[i] = f2b(fmaxf(fmaf(r[i], scale, shift), 0.0f));
  }
  *(ushort4*)&out[idx] = o;
}

// ---------------- bf16 MFMA GEMM (templated BN), swizzled LDS + XCD mapping ----
// C(f32) or C16(bf16) [M,NC] (+)= A[M,K](bf16, lda) * Bt[NC,K](bf16)^T (+bias)
// K = B row stride AND loop bound for blocks with col0 < 1024;
// Ksmall = loop bound for col0 >= 1024 (variable-K concat; pass Ksmall=K otherwise).
template<int BN>
__global__ __launch_bounds__(256) void gemm_bf16_k(
    const unsigned short* __restrict__ A, const unsigned short* __restrict__ Bt,
    float* __restrict__ C, unsigned short* __restrict__ C16,
    const float* __restrict__ bias,
    int M, int K, int Ksmall, int lda, int NC, int ldc, int acc, int nrowb, int ncolb)
{
  const int b   = blockIdx.x;
  const int xcd = b & 7;
  const int j   = b >> 3;
  const int col_b = j % ncolb;
  const int row_b = (j / ncolb) * 8 + xcd;
  if (row_b >= nrowb) return;

  constexpr int MI = (BN == 128) ? 4 : 2;
  __shared__ unsigned short As[128 * 32];
  __shared__ unsigned short Bs[BN * 32];
  const int row0 = row_b * 128;
  const int col0 = col_b * BN;
  const int Kthis = (col0 < 1024) ? K : Ksmall;
  const int t    = threadIdx.x;
  const int lane = t & 63;
  const int w    = t >> 6;
  const int wro  = (BN == 128) ? (w >> 1) * 64 : w * 32;
  const int wco  = (BN == 128) ? (w & 1) * 64 : 0;
  const int q    = lane >> 4;
  const int l16  = lane & 15;

  f32x4 accr[MI][4] = {};

  for (int k0 = 0; k0 < Kthis; k0 += 32) {
    #pragma unroll
    for (int i = 0; i < 2; i++) {
      int s  = t + i * 256;
      int r  = s >> 2, cq = s & 3;
      int kq = (cq - (r >> 1)) & 3;
      int gr = row0 + r; if (gr > M - 1) gr = M - 1;
      gld_lds16(A + (size_t)gr * lda + k0 + kq * 8, As + (size_t)s * 8);
    }
    #pragma unroll
    for (int i = 0; i < BN / 64; i++) {
      int s  = t + i * 256;
      int r  = s >> 2, cq = s & 3;
      int kq = (cq - (r >> 1)) & 3;
      gld_lds16(Bt + (size_t)(col0 + r) * K + k0 + kq * 8, Bs + (size_t)s * 8);
    }
    __syncthreads();

    bf16x8 af[MI], bf[4];
    #pragma unroll
    for (int mi = 0; mi < MI; mi++) {
      int r = wro + mi * 16 + l16;
      int qs = (q + (r >> 1)) & 3;
      af[mi] = *(const bf16x8*)&As[r * 32 + qs * 8];
    }
    #pragma unroll
    for (int ni = 0; ni < 4; ni++) {
      int r = wco + ni * 16 + l16;
      int qs = (q + (r >> 1)) & 3;
      bf[ni] = *(const bf16x8*)&Bs[r * 32 + qs * 8];
    }
    #pragma unroll
    for (int mi = 0; mi < MI; mi++)
      #pragma unroll
      for (int ni = 0; ni < 4; ni++)
        accr[mi][ni] = __builtin_amdgcn_mfma_f32_16x16x32_bf16(
            af[mi], bf[ni], accr[mi][ni], 0, 0, 0);
    __syncthreads();
  }

  #pragma unroll
  for (int mi = 0; mi < MI; mi++) {
    #pragma unroll
    for (int ni = 0; ni < 4; ni++) {
      int col = col0 + wco + ni * 16 + l16;
      #pragma unroll
      for (int r = 0; r < 4; r++) {
        int row = row0 + wro + mi * 16 + q * 4 + r;
        if (row < M) {
          float v = accr[mi][ni][r];
          if (C16) {
            C16[(size_t)row * ldc + col] = f2b(v);
          } else {
            float* cp = &C[(size_t)row * ldc + col];
            if (acc)       *cp += v;
            else if (bias) *cp  = v + bias[col];
            else           *cp  = v;
          }
        }
      }
    }
  }
}

// ---------------- LSTM cell part 1 (gate order f|g|i|o; bias added here) --------
__global__ __launch_bounds__(256) void cell1_k(
    const float* __restrict__ gates, const float* __restrict__ lb,
    const float* __restrict__ cin,
    float* __restrict__ cout, unsigned short* __restrict__ cout16, int ld16,
    int rows, int hasC)
{
  size_t gid = (size_t)blockIdx.x * 256 + threadIdx.x;
  if (gid >= (size_t)rows * HID) return;
  size_t row = gid >> 9;
  int    col = (int)(gid & (HID - 1));
  const float* g = &gates[row * G4];
  float ig = sigmoidf_(g[I_OFF + col] + lb[col]);
  float gg = tanhf(g[G_OFF + col] + lb[2 * HID + col]);
  float c;
  if (hasC) {
    float fg = sigmoidf_(g[F_OFF + col] + lb[HID + col]);
    c = fg * cin[gid] + ig * gg;
  } else {
    c = ig * gg;
  }
  cout[gid] = c;
  cout16[row * ld16 + col] = f2b(c);
}

// ---------------- LSTM cell part 2 (optional fp32 hy, optional strided bf16) ----
__global__ __launch_bounds__(256) void cell2_k(
    const float* __restrict__ gates, const float* __restrict__ lb,
    const float* __restrict__ cy,
    float* __restrict__ hy, unsigned short* __restrict__ hy16, int ld16, int rows)
{
  size_t gid = (size_t)blockIdx.x * 256 + threadIdx.x;
  if (gid >= (size_t)rows * HID) return;
  size_t row = gid >> 9;
  int    col = (int)(gid & (HID - 1));
  float og = sigmoidf_(gates[row * G4 + O_OFF + col] + lb[3 * HID + col]);
  float h = og * tanhf(cy[gid]);
  if (hy)   hy[gid] = h;
  if (hy16) hy16[row * ld16 + col] = f2b(h);
}

// ---------------- fused final cell2 + output projection ----------------
// one wave per row: hy = sigma(o+b)*tanh(c) computed in-register, then 12 dots.
__global__ __launch_bounds__(256) void cellout_k(
    const float* __restrict__ gates, const float* __restrict__ lb,
    const float* __restrict__ cy,
    const float* __restrict__ W, const float* __restrict__ b,
    float* __restrict__ out, int rows)
{
  int wave = (int)(((size_t)blockIdx.x * 256 + threadIdx.x) >> 6);
  int lane = threadIdx.x & 63;
  if (wave >= rows) return;
  const float* g  = &gates[(size_t)wave * G4 + O_OFF];
  const float* cr = &cy[(size_t)wave * HID];
  float hy[8];
  #pragma unroll
  for (int j = 0; j < 8; j++) {
    int k = lane + j * 64;
    float og = sigmoidf_(g[k] + lb[3 * HID + k]);
    hy[j] = og * tanhf(cr[k]);
  }
  float acc[12] = {};
  #pragma unroll
  for (int j = 0; j < 8; j++) {
    int k = lane + j * 64;
    const float* wr = &W[k * 12];
    #pragma unroll
    for (int p = 0; p < 12; p++) acc[p] = fmaf(hy[j], wr[p], acc[p]);
  }
  #pragma unroll
  for (int p = 0; p < 12; p++) {
    float v = acc[p];
    #pragma unroll
    for (int off = 32; off > 0; off >>= 1) v += __shfl_down(v, off);
    if (lane == 0) out[(size_t)wave * 12 + p] = v + b[p];
  }
}

extern "C" void kernel_launch(void* const* d_in, const int* in_sizes, int n_in,
                              void* d_out, int out_size, void* d_ws, size_t ws_size,
                              hipStream_t stream) {
  const float* x     = (const float*)d_in[0];
  const int*   ei    = (const int*)d_in[1];
  const float* ew    = (const float*)d_in[2];
  const float* gcn0W = (const float*)d_in[3];
  const float* gcnW  = (const float*)d_in[5];
  const float* gamma = (const float*)d_in[7];
  const float* beta  = (const float*)d_in[8];
  const float* wih   = (const float*)d_in[9];
  const float* whh   = (const float*)d_in[10];
  const float* wch   = (const float*)d_in[11];
  const float* lstmb = (const float*)d_in[12];
  const float* outW  = (const float*)d_in[13];
  const float* outb  = (const float*)d_in[14];
  float* out = (float*)d_out;

  const int* src = ei;
  const int* dst = ei + N_EDGES;

  const int CH = (ws_size >= (size_t)215000000) ? 10000 : 5000;
  const int NCHUNK = N_NODES / CH;

  // -------- workspace layout --------
  const size_t NH = (size_t)N_NODES * HID;
  float* ws = (float*)d_ws;
  float* gates = ws;                                 // CH*2048 fp32
  float* bufH  = gates + (size_t)CH * G4;            // NH fp32 region (bf16 H / cbuf)
  unsigned short* hbA16 = (unsigned short*)(bufH + NH);
  unsigned short* hbB16 = hbA16 + NH;
  unsigned short* x16   = hbB16 + NH;
  unsigned short* g0t   = x16 + (size_t)N_NODES * IN_CH;
  unsigned short* g1t   = g0t   + 512 * 64;
  unsigned short* g2t   = g1t   + 512 * 512;
  unsigned short* wih0t = g2t   + 512 * 512;             // [2048,512] f|g|i|o rows
  unsigned short* wcat3 = wih0t + (size_t)2048 * 512;    // [2048,1536] fused L1 B
  unsigned short* wch0ot= wcat3 + (size_t)2048 * 1536;   // [512,512]
  unsigned short* wch1ot= wch0ot + 512 * 512;            // [512,512]
  unsigned short* wend  = wch1ot + 512 * 512;
  unsigned short *a16, *tail16;                          // concat [CH,1536]
  if (CH == 5000) {
    a16  = hbB16;
    tail16 = wend;
  } else {
    a16  = wend;
    tail16 = a16 + (size_t)CH * 1536;
  }
  float* stats = (float*)tail16;
  int*   csr   = (int*)(stats + 1024);
  int*   counts  = csr;
  int*   offsets = csr + 20032;
  int*   cpos    = csr + 40064;
  int*   s_s     = csr + 60096;
  float* w_s     = (float*)(csr + 380096);

  unsigned short* bufH16 = (unsigned short*)bufH;  // bf16 H during GCN
  float* cbuf = bufH;                              // CH*512 fp32 during LSTM

  const dim3 blk(256);
  auto gemm128 = [&](const unsigned short* A, const unsigned short* Bt, float* C,
                     unsigned short* C16, const float* bias,
                     int M, int K, int Ksmall, int lda, int NC, int ldc, int acc) {
    int nrowb = (M + 127) / 128;
    int ncolb = NC / 128;
    int nblocks = 8 * ((nrowb + 7) / 8) * ncolb;
    hipLaunchKernelGGL((gemm_bf16_k<128>), dim3(nblocks), blk, 0, stream,
                       A, Bt, C, C16, bias, M, K, Ksmall, lda, NC, ldc, acc, nrowb, ncolb);
  };
  auto gemm64 = [&](const unsigned short* A, const unsigned short* Bt, float* C,
                    unsigned short* C16, const float* bias,
                    int M, int K, int lda, int NC, int ldc, int acc) {
    int nrowb = (M + 127) / 128;
    int ncolb = NC / 64;
    int nblocks = 8 * ((nrowb + 7) / 8) * ncolb;
    hipLaunchKernelGGL((gemm_bf16_k<64>), dim3(nblocks), blk, 0, stream,
                       A, Bt, C, C16, bias, M, K, K, lda, NC, ldc, acc, nrowb, ncolb);
  };
  auto tcvt = [&](const float* W, unsigned short* Wt, int K, int NC, int ldw, int ldo) {
    dim3 grid((NC + 31) / 32, (K + 31) / 32);
    hipLaunchKernelGGL(tcvt_k, grid, dim3(32, 8), 0, stream, W, Wt, K, NC, ldw, ldo);
  };
  auto zero = [&](float* p, size_t n) {
    hipLaunchKernelGGL(zero_k, dim3((unsigned)((n / 4 + 255) / 256)), blk, 0, stream, p, n);
  };

  // -------- weight prep (gate order f|g|i|o) --------
  const float* wih1 = wih + (size_t)HID * G4;
  const float* whh1 = whh + (size_t)HID * G4;
  const float* wch1 = wch + (size_t)HID * 3 * HID;
  tcvt(gcn0W, g0t, IN_CH, HID, HID, IN_CH);
  tcvt(gcnW,                     g1t, HID, HID, HID, HID);
  tcvt(gcnW + (size_t)HID * HID, g2t, HID, HID, HID, HID);
  tcvt(wih + HID,     wih0t + (size_t)F_OFF * 512, HID, HID, G4, HID);
  tcvt(wih + 2 * HID, wih0t + (size_t)G_OFF * 512, HID, HID, G4, HID);
  tcvt(wih,           wih0t + (size_t)I_OFF * 512, HID, HID, G4, HID);
  tcvt(wih + 3 * HID, wih0t + (size_t)O_OFF * 512, HID, HID, G4, HID);
  tcvt(wih1 + HID,     wcat3 + (size_t)F_OFF * 1536,        HID, HID, G4, 1536);
  tcvt(whh1 + HID,     wcat3 + (size_t)F_OFF * 1536 + 512,  HID, HID, G4, 1536);
  tcvt(wch1 + HID,     wcat3 + (size_t)F_OFF * 1536 + 1024, HID, HID, 3 * HID, 1536);
  tcvt(wih1 + 2 * HID, wcat3 + (size_t)G_OFF * 1536,        HID, HID, G4, 1536);
  tcvt(whh1 + 2 * HID, wcat3 + (size_t)G_OFF * 1536 + 512,  HID, HID, G4, 1536);
  tcvt(wch1,           wcat3 + (size_t)G_OFF * 1536 + 1024, HID, HID, 3 * HID, 1536);
  tcvt(wih1,           wcat3 + (size_t)I_OFF * 1536,        HID, HID, G4, 1536);
  tcvt(whh1,           wcat3 + (size_t)I_OFF * 1536 + 512,  HID, HID, G4, 1536);
  tcvt(wih1 + 3 * HID, wcat3 + (size_t)O_OFF * 1536,        HID, HID, G4, 1536);
  tcvt(whh1 + 3 * HID, wcat3 + (size_t)O_OFF * 1536 + 512,  HID, HID, G4, 1536);
  tcvt(wch + 2 * HID,  wch0ot, HID, HID, 3 * HID, HID);   // Wch0 o-peephole
  tcvt(wch1 + 2 * HID, wch1ot, HID, HID, 3 * HID, HID);   // Wch1 o-peephole
  hipLaunchKernelGGL(cvt_k, dim3((N_NODES * IN_CH / 4 + 255) / 256), blk, 0, stream,
                     x, x16, (size_t)N_NODES * IN_CH);

  // -------- CSR build --------
  const int e_blocks = (N_EDGES + 255) / 256;
  zero((float*)counts, N_NODES);
  hipLaunchKernelGGL(hist_k, dim3(e_blocks), blk, 0, stream, dst, counts);
  hipLaunchKernelGGL(scan_k, dim3(1), dim3(1024), 0, stream, counts, offsets, cpos, N_NODES);
  hipLaunchKernelGGL(fill_k, dim3(e_blocks), blk, 0, stream, src, dst, ew, cpos, s_s, w_s);

  // -------- GCN layer 0: gather-first (linearity), 8x less gather traffic ------
  // xg = S·x (bf16, 64 cols) -> H = xg @ W0 (bf16) -> BN
  hipLaunchKernelGGL(gather64_k, dim3(N_NODES / 4), dim3(64), 0, stream,
                     x16, offsets, s_s, w_s, hbB16);
  gemm64(hbB16, g0t, nullptr, bufH16, nullptr, N_NODES, IN_CH, IN_CH, HID, HID, 0);
  zero(stats, 2 * HID);
  hipLaunchKernelGGL(bn_stats_k, dim3(8, 64), blk, 0, stream, bufH16, stats, N_NODES);
  hipLaunchKernelGGL(bn_apply_k, dim3((unsigned)(NH / 4 / 256)), blk, 0, stream,
                     bufH16, stats, gamma, beta, hbA16, N_NODES);

  // -------- GCN layers 1,2: GEMM -> gather -> BN --------
  const unsigned short* gWt2[2] = {g1t, g2t};
  const unsigned short* gA2[2]  = {hbA16, hbB16};
  unsigned short*       gXW2[2] = {hbB16, hbA16};
  unsigned short*       gO2[2]  = {hbB16, hbA16};
  for (int l = 0; l < 2; l++) {
    gemm64(gA2[l], gWt2[l], nullptr, gXW2[l], nullptr, N_NODES, HID, HID, HID, HID, 0);
    hipLaunchKernelGGL(gather_k, dim3(N_NODES), dim3(128), 0, stream,
                       gXW2[l], offsets, s_s, w_s, bufH16);
    zero(stats, 2 * HID);
    hipLaunchKernelGGL(bn_stats_k, dim3(8, 64), blk, 0, stream, bufH16, stats, N_NODES);
    hipLaunchKernelGGL(bn_apply_k, dim3((unsigned)(NH / 4 / 256)), blk, 0, stream,
                       bufH16, stats, gamma + (l + 1) * HID, beta + (l + 1) * HID,
                       gO2[l], N_NODES);
  }
  unsigned short* hfin16 = hbA16;

  // -------- LSTM + output, chunked --------
  for (int ci = 0; ci < NCHUNK; ci++) {
    const int r0 = ci * CH;
    const unsigned short* h_c = hfin16 + (size_t)r0 * HID;
    const int cell_blocks = (int)(((size_t)CH * HID + 255) / 256);
    const int cpy_blocks  = (int)(((size_t)CH * HID / 4 + 255) / 256);

    // a16 row = [ h(0:512) | hy0(512:1024) | c(1024:1536) ]
    hipLaunchKernelGGL(cpy16_k, dim3(cpy_blocks), blk, 0, stream, h_c, a16, CH, 1536);

    // layer 0 (h=c=0): gates = h@Wih0 (bias added in cells)
    gemm128(h_c, wih0t, gates, nullptr, nullptr, CH, HID, HID, HID, G4, G4, 0);
    hipLaunchKernelGGL(cell1_k, dim3(cell_blocks), blk, 0, stream,
                       gates, lstmb, (const float*)nullptr, cbuf, a16 + 1024, 1536, CH, 0);
    // o peephole L0: gates[:,O] += c0 @ Wch0_o
    gemm64(a16 + 1024, wch0ot, gates + O_OFF, nullptr, nullptr,
           CH, HID, 1536, HID, G4, 1);
    // hy0 -> bf16 concat slice only (fp32 hy0 is never read)
    hipLaunchKernelGGL(cell2_k, dim3(cell_blocks), blk, 0, stream,
                       gates, lstmb, cbuf, (float*)nullptr, a16 + 512, 1536, CH);

    // layer 1 fused: gates = [h|hy0|c0] @ wcat3 ; f,g cols K=1536, i,o cols K=1024
    gemm128(a16, wcat3, gates, nullptr, nullptr, CH, 1536, 1024, 1536, G4, G4, 0);
    hipLaunchKernelGGL(cell1_k, dim3(cell_blocks), blk, 0, stream,
                       gates, lstmb + G4, cbuf, cbuf, a16 + 1024, 1536, CH, 1);
    // o peephole L1: gates[:,O] += c1 @ Wch1_o
    gemm64(a16 + 1024, wch1ot, gates + O_OFF, nullptr, nullptr,
           CH, HID, 1536, HID, G4, 1);
    // fused cell2 + output projection
    hipLaunchKernelGGL(cellout_k, dim3((CH * 64 + 255) / 256), blk, 0, stream,
                       gates, lstmb + G4, cbuf, outW, outb, out + (size_t)r0 * 12, CH);
  }
}

// Round 13
// 1016.394 us; speedup vs baseline: 1.4061x; 1.0064x over previous
//
#include <hip/hip_runtime.h>
#include <cstddef>

#define N_NODES 20000
#define N_EDGES 320000
#define IN_CH   64
#define HID     512
#define G4      2048
#define BN_EPS  1e-5f
// gate order in gates buffer: [f | g | i | o]
#define F_OFF   0
#define G_OFF   512
#define I_OFF   1024
#define O_OFF   1536

typedef __attribute__((ext_vector_type(8))) __bf16 bf16x8;
typedef __attribute__((ext_vector_type(4))) float f32x4;

__device__ __forceinline__ float sigmoidf_(float x) {
  return 1.0f / (1.0f + expf(-x));
}

// fp32 -> bf16 (RNE)
__device__ __forceinline__ unsigned short f2b(float f) {
  unsigned int u = __float_as_uint(f);
  u += 0x7FFFu + ((u >> 16) & 1u);
  return (unsigned short)(u >> 16);
}
__device__ __forceinline__ float b2f(unsigned short u) {
  return __uint_as_float(((unsigned int)u) << 16);
}

__device__ __forceinline__ void gld_lds16(const unsigned short* g, unsigned short* l) {
  __builtin_amdgcn_global_load_lds(
      (const __attribute__((address_space(1))) unsigned int*)(const void*)g,
      (__attribute__((address_space(3))) unsigned int*)(void*)l, 16, 0, 0);
}

// ---------------- zero fill ----------------
__global__ __launch_bounds__(256) void zero_k(float* __restrict__ p, size_t n) {
  size_t i = ((size_t)blockIdx.x * 256 + threadIdx.x) * 4;
  if (i + 3 < n) {
    *(float4*)&p[i] = make_float4(0.f, 0.f, 0.f, 0.f);
  } else {
    for (; i < n; i++) p[i] = 0.f;
  }
}

// ---------------- f32 -> bf16 ----------------
__global__ __launch_bounds__(256) void cvt_k(const float* __restrict__ in,
                                             unsigned short* __restrict__ out, size_t n) {
  size_t i = ((size_t)blockIdx.x * 256 + threadIdx.x) * 4;
  if (i + 3 < n) {
    const float4 v = *(const float4*)&in[i];
    ushort4 o; o.x = f2b(v.x); o.y = f2b(v.y); o.z = f2b(v.z); o.w = f2b(v.w);
    *(ushort4*)&out[i] = o;
  } else {
    for (; i < n; i++) out[i] = f2b(in[i]);
  }
}

// ---------------- transpose + cvt: Wt[n*ldo + k] = bf16(W[k*ldw + n]) ----------------
__global__ void tcvt_k(const float* __restrict__ W, unsigned short* __restrict__ Wt,
                       int K, int NC, int ldw, int ldo) {
  __shared__ float tile[32][33];
  const int n0 = blockIdx.x * 32, k0 = blockIdx.y * 32;
  const int tx = threadIdx.x, ty = threadIdx.y;  // 32 x 8
  #pragma unroll
  for (int i = 0; i < 32; i += 8) {
    int k = k0 + ty + i, n = n0 + tx;
    tile[ty + i][tx] = (k < K && n < NC) ? W[(size_t)k * ldw + n] : 0.f;
  }
  __syncthreads();
  #pragma unroll
  for (int i = 0; i < 32; i += 8) {
    int n = n0 + ty + i, k = k0 + tx;
    if (n < NC && k < K) Wt[(size_t)n * ldo + k] = f2b(tile[tx][ty + i]);
  }
}

// ---------------- CSR build ----------------
__global__ __launch_bounds__(256) void hist_k(const int* __restrict__ dst,
                                              int* __restrict__ counts) {
  int e = blockIdx.x * 256 + threadIdx.x;
  if (e < N_EDGES) atomicAdd(&counts[dst[e]], 1);
}

__global__ __launch_bounds__(1024) void scan_k(const int* __restrict__ counts,
                                               int* __restrict__ offsets,
                                               int* __restrict__ pos, int n) {
  __shared__ int tmp[1024];
  __shared__ int carry_s;
  const int tid = threadIdx.x;
  if (tid == 0) carry_s = 0;
  __syncthreads();
  for (int base = 0; base < n; base += 1024) {
    int i = base + tid;
    int v = (i < n) ? counts[i] : 0;
    tmp[tid] = v;
    __syncthreads();
    #pragma unroll
    for (int off = 1; off < 1024; off <<= 1) {
      int t = (tid >= off) ? tmp[tid - off] : 0;
      __syncthreads();
      tmp[tid] += t;
      __syncthreads();
    }
    if (i < n) {
      int excl = carry_s + tmp[tid] - v;
      offsets[i] = excl;
      pos[i] = excl;
    }
    __syncthreads();
    if (tid == 1023) carry_s += tmp[1023];
    __syncthreads();
  }
  if (tid == 0) offsets[n] = carry_s;
}

__global__ __launch_bounds__(256) void fill_k(
    const int* __restrict__ src, const int* __restrict__ dst,
    const float* __restrict__ ew, int* __restrict__ pos,
    int* __restrict__ s_s, float* __restrict__ w_s) {
  int e = blockIdx.x * 256 + threadIdx.x;
  if (e >= N_EDGES) return;
  int p = atomicAdd(&pos[dst[e]], 1);
  s_s[p] = src[e];
  w_s[p] = ew[e];
}

// ---------------- L0 gather on 64-col input: xg = S·x (linearity) ----------------
__global__ __launch_bounds__(64) void gather64_k(
    const unsigned short* __restrict__ x16, const int* __restrict__ offsets,
    const int* __restrict__ s_s, const float* __restrict__ w_s,
    unsigned short* __restrict__ xg) {
  const int sub = threadIdx.x >> 4;
  const int cg  = threadIdx.x & 15;
  const int n   = blockIdx.x * 4 + sub;
  const int beg = offsets[n], end = offsets[n + 1];
  float4 acc = make_float4(0.f, 0.f, 0.f, 0.f);
  for (int i = beg; i < end; i++) {
    const int   s = s_s[i];
    const float w = w_s[i];
    const ushort4 v = *(const ushort4*)&x16[(size_t)s * IN_CH + cg * 4];
    acc.x = fmaf(w, b2f(v.x), acc.x);
    acc.y = fmaf(w, b2f(v.y), acc.y);
    acc.z = fmaf(w, b2f(v.z), acc.z);
    acc.w = fmaf(w, b2f(v.w), acc.w);
  }
  ushort4 o; o.x = f2b(acc.x); o.y = f2b(acc.y); o.z = f2b(acc.z); o.w = f2b(acc.w);
  *(ushort4*)&xg[(size_t)n * IN_CH + cg * 4] = o;
}

// ---------------- aggregation gather (bf16 XW -> bf16 H) ----------------
__global__ __launch_bounds__(128) void gather_k(
    const unsigned short* __restrict__ XW, const int* __restrict__ offsets,
    const int* __restrict__ s_s, const float* __restrict__ w_s,
    unsigned short* __restrict__ H) {
  const int n = blockIdx.x;
  const int t = threadIdx.x;
  const int beg = offsets[n], end = offsets[n + 1];
  float4 acc = make_float4(0.f, 0.f, 0.f, 0.f);
  for (int i = beg; i < end; i++) {
    const int   s = s_s[i];
    const float w = w_s[i];
    const ushort4 v = *(const ushort4*)&XW[(size_t)s * HID + t * 4];
    acc.x = fmaf(w, b2f(v.x), acc.x);
    acc.y = fmaf(w, b2f(v.y), acc.y);
    acc.z = fmaf(w, b2f(v.z), acc.z);
    acc.w = fmaf(w, b2f(v.w), acc.w);
  }
  ushort4 o; o.x = f2b(acc.x); o.y = f2b(acc.y); o.z = f2b(acc.z); o.w = f2b(acc.w);
  *(ushort4*)&H[(size_t)n * HID + t * 4] = o;
}

// ---------------- BN stats over bf16 H ----------------
__global__ __launch_bounds__(256) void bn_stats_k(
    const unsigned short* __restrict__ H, float* __restrict__ stats, int N)
{
  const int tx = threadIdx.x & 63;
  const int ty = threadIdx.x >> 6;
  const int col = blockIdx.x * 64 + tx;
  float s1 = 0.f, s2 = 0.f;
  for (int r = blockIdx.y * 4 + ty; r < N; r += gridDim.y * 4) {
    float v = b2f(H[(size_t)r * HID + col]);
    s1 += v; s2 += v * v;
  }
  __shared__ float red[2][4][64];
  red[0][ty][tx] = s1;
  red[1][ty][tx] = s2;
  __syncthreads();
  if (ty == 0) {
    s1 = red[0][0][tx] + red[0][1][tx] + red[0][2][tx] + red[0][3][tx];
    s2 = red[1][0][tx] + red[1][1][tx] + red[1][2][tx] + red[1][3][tx];
    atomicAdd(&stats[col], s1);
    atomicAdd(&stats[HID + col], s2);
  }
}

// ---------------- BN apply + ReLU: bf16 H -> bf16 h ----------------
__global__ __launch_bounds__(256) void bn_apply_k(
    const unsigned short* __restrict__ H, const float* __restrict__ stats,
    const float* __restrict__ gamma, const float* __restrict__ beta,
    unsigned short* __restrict__ out, int N)
{
  size_t gid = (size_t)blockIdx.x * 256 + threadIdx.x;
  size_t idx = gid * 4;
  if (idx >= (size_t)N * HID) return;
  int col = (int)(idx & (HID - 1));
  const ushort4 v = *(const ushort4*)&H[idx];
  float r[4] = {b2f(v.x), b2f(v.y), b2f(v.z), b2f(v.w)};
  ushort4 o;
  unsigned short* op = &o.x;
  #pragma unroll
  for (int i = 0; i < 4; i++) {
    int c = col + i;
    float mean = stats[c] * (1.0f / N);
    float var  = stats[HID + c] * (1.0f / N) - mean * mean;
    float scale = gamma[c] / sqrtf(var + BN_EPS);
    float shift = beta[c] - mean * scale;
    op[i] = f2b(fmaxf(fmaf(r[i], scale, shift), 0.0f));
  }
  *(ushort4*)&out[idx] = o;
}

// ---------------- bf16 MFMA GEMM (templated BN), swizzled LDS + XCD mapping ----
// C(f32) or C16(bf16) [M,NC] (+)= A[M,K] * Bt[NC,K]^T (+bias)
// Split-A: k < ksplit reads A(lda); k >= ksplit reads A2(lda2) at col k-ksplit.
// Variable-K: blocks with col0 >= 1024 run Ksmall instead of K (K = B row stride).
template<int BN>
__global__ __launch_bounds__(256) void gemm_bf16_k(
    const unsigned short* __restrict__ A, int lda,
    const unsigned short* __restrict__ A2, int lda2, int ksplit,
    const unsigned short* __restrict__ Bt,
    float* __restrict__ C, unsigned short* __restrict__ C16,
    const float* __restrict__ bias,
    int M, int K, int Ksmall, int NC, int ldc, int acc, int nrowb, int ncolb)
{
  const int b   = blockIdx.x;
  const int xcd = b & 7;
  const int j   = b >> 3;
  const int col_b = j % ncolb;
  const int row_b = (j / ncolb) * 8 + xcd;
  if (row_b >= nrowb) return;

  constexpr int MI = (BN == 128) ? 4 : 2;
  __shared__ unsigned short As[128 * 32];
  __shared__ unsigned short Bs[BN * 32];
  const int row0 = row_b * 128;
  const int col0 = col_b * BN;
  const int Kthis = (col0 < 1024) ? K : Ksmall;
  const int t    = threadIdx.x;
  const int lane = t & 63;
  const int w    = t >> 6;
  const int wro  = (BN == 128) ? (w >> 1) * 64 : w * 32;
  const int wco  = (BN == 128) ? (w & 1) * 64 : 0;
  const int q    = lane >> 4;
  const int l16  = lane & 15;

  f32x4 accr[MI][4] = {};

  for (int k0 = 0; k0 < Kthis; k0 += 32) {
    #pragma unroll
    for (int i = 0; i < 2; i++) {
      int s  = t + i * 256;
      int r  = s >> 2, cq = s & 3;
      int kq = (cq - (r >> 1)) & 3;
      int gr = row0 + r; if (gr > M - 1) gr = M - 1;
      int kk = k0 + kq * 8;
      const unsigned short* bp = (kk < ksplit) ? A : A2;
      size_t off = (kk < ksplit) ? ((size_t)gr * lda + kk)
                                 : ((size_t)gr * lda2 + (kk - ksplit));
      gld_lds16(bp + off, As + (size_t)s * 8);
    }
    #pragma unroll
    for (int i = 0; i < BN / 64; i++) {
      int s  = t + i * 256;
      int r  = s >> 2, cq = s & 3;
      int kq = (cq - (r >> 1)) & 3;
      gld_lds16(Bt + (size_t)(col0 + r) * K + k0 + kq * 8, Bs + (size_t)s * 8);
    }
    __syncthreads();

    bf16x8 af[MI], bf[4];
    #pragma unroll
    for (int mi = 0; mi < MI; mi++) {
      int r = wro + mi * 16 + l16;
      int qs = (q + (r >> 1)) & 3;
      af[mi] = *(const bf16x8*)&As[r * 32 + qs * 8];
    }
    #pragma unroll
    for (int ni = 0; ni < 4; ni++) {
      int r = wco + ni * 16 + l16;
      int qs = (q + (r >> 1)) & 3;
      bf[ni] = *(const bf16x8*)&Bs[r * 32 + qs * 8];
    }
    #pragma unroll
    for (int mi = 0; mi < MI; mi++)
      #pragma unroll
      for (int ni = 0; ni < 4; ni++)
        accr[mi][ni] = __builtin_amdgcn_mfma_f32_16x16x32_bf16(
            af[mi], bf[ni], accr[mi][ni], 0, 0, 0);
    __syncthreads();
  }

  #pragma unroll
  for (int mi = 0; mi < MI; mi++) {
    #pragma unroll
    for (int ni = 0; ni < 4; ni++) {
      int col = col0 + wco + ni * 16 + l16;
      #pragma unroll
      for (int r = 0; r < 4; r++) {
        int row = row0 + wro + mi * 16 + q * 4 + r;
        if (row < M) {
          float v = accr[mi][ni][r];
          if (C16) {
            C16[(size_t)row * ldc + col] = f2b(v);
          } else {
            float* cp = &C[(size_t)row * ldc + col];
            if (acc)       *cp += v;
            else if (bias) *cp  = v + bias[col];
            else           *cp  = v;
          }
        }
      }
    }
  }
}

// ---------------- LSTM cell part 1 (gate order f|g|i|o; bias added here) --------
__global__ __launch_bounds__(256) void cell1_k(
    const float* __restrict__ gates, const float* __restrict__ lb,
    const float* __restrict__ cin,
    float* __restrict__ cout, unsigned short* __restrict__ cout16, int ld16,
    int rows, int hasC)
{
  size_t gid = (size_t)blockIdx.x * 256 + threadIdx.x;
  if (gid >= (size_t)rows * HID) return;
  size_t row = gid >> 9;
  int    col = (int)(gid & (HID - 1));
  const float* g = &gates[row * G4];
  float ig = sigmoidf_(g[I_OFF + col] + lb[col]);
  float gg = tanhf(g[G_OFF + col] + lb[2 * HID + col]);
  float c;
  if (hasC) {
    float fg = sigmoidf_(g[F_OFF + col] + lb[HID + col]);
    c = fg * cin[gid] + ig * gg;
  } else {
    c = ig * gg;
  }
  cout[gid] = c;
  cout16[row * ld16 + col] = f2b(c);
}

// ---------------- LSTM cell part 2: hy16 = sigma(gates_O + obuf + b_o)*tanh(c) ---
__global__ __launch_bounds__(256) void cell2_k(
    const float* __restrict__ gates, const float* __restrict__ obuf,
    const float* __restrict__ lb, const float* __restrict__ cy,
    unsigned short* __restrict__ hy16, int ld16, int rows)
{
  size_t gid = (size_t)blockIdx.x * 256 + threadIdx.x;
  if (gid >= (size_t)rows * HID) return;
  size_t row = gid >> 9;
  int    col = (int)(gid & (HID - 1));
  float og = sigmoidf_(gates[row * G4 + O_OFF + col] + obuf[gid] + lb[3 * HID + col]);
  float h = og * tanhf(cy[gid]);
  hy16[row * ld16 + col] = f2b(h);
}

// ---------------- fused final cell2 + output projection ----------------
__global__ __launch_bounds__(256) void cellout_k(
    const float* __restrict__ gates, const float* __restrict__ obuf,
    const float* __restrict__ lb, const float* __restrict__ cy,
    const float* __restrict__ W, const float* __restrict__ b,
    float* __restrict__ out, int rows)
{
  int wave = (int)(((size_t)blockIdx.x * 256 + threadIdx.x) >> 6);
  int lane = threadIdx.x & 63;
  if (wave >= rows) return;
  const float* g  = &gates[(size_t)wave * G4 + O_OFF];
  const float* ob = &obuf[(size_t)wave * HID];
  const float* cr = &cy[(size_t)wave * HID];
  float hy[8];
  #pragma unroll
  for (int j = 0; j < 8; j++) {
    int k = lane + j * 64;
    float og = sigmoidf_(g[k] + ob[k] + lb[3 * HID + k]);
    hy[j] = og * tanhf(cr[k]);
  }
  float acc[12] = {};
  #pragma unroll
  for (int j = 0; j < 8; j++) {
    int k = lane + j * 64;
    const float* wr = &W[k * 12];
    #pragma unroll
    for (int p = 0; p < 12; p++) acc[p] = fmaf(hy[j], wr[p], acc[p]);
  }
  #pragma unroll
  for (int p = 0; p < 12; p++) {
    float v = acc[p];
    #pragma unroll
    for (int off = 32; off > 0; off >>= 1) v += __shfl_down(v, off);
    if (lane == 0) out[(size_t)wave * 12 + p] = v + b[p];
  }
}

extern "C" void kernel_launch(void* const* d_in, const int* in_sizes, int n_in,
                              void* d_out, int out_size, void* d_ws, size_t ws_size,
                              hipStream_t stream) {
  const float* x     = (const float*)d_in[0];
  const int*   ei    = (const int*)d_in[1];
  const float* ew    = (const float*)d_in[2];
  const float* gcn0W = (const float*)d_in[3];
  const float* gcnW  = (const float*)d_in[5];
  const float* gamma = (const float*)d_in[7];
  const float* beta  = (const float*)d_in[8];
  const float* wih   = (const float*)d_in[9];
  const float* whh   = (const float*)d_in[10];
  const float* wch   = (const float*)d_in[11];
  const float* lstmb = (const float*)d_in[12];
  const float* outW  = (const float*)d_in[13];
  const float* outb  = (const float*)d_in[14];
  float* out = (float*)d_out;

  const int* src = ei;
  const int* dst = ei + N_EDGES;

  const int CH = (ws_size >= (size_t)215000000) ? 10000 : 5000;
  const int NCHUNK = N_NODES / CH;

  // -------- workspace layout --------
  const size_t NH = (size_t)N_NODES * HID;
  float* ws = (float*)d_ws;
  float* gates = ws;                                 // CH*2048 fp32
  float* bufH  = gates + (size_t)CH * G4;            // NH fp32 (bf16 H / cbuf+obuf)
  unsigned short* hbA16 = (unsigned short*)(bufH + NH);
  unsigned short* hbB16 = hbA16 + NH;
  unsigned short* x16   = hbB16 + NH;
  unsigned short* g0t   = x16 + (size_t)N_NODES * IN_CH;
  unsigned short* g1t   = g0t   + 512 * 64;
  unsigned short* g2t   = g1t   + 512 * 512;
  unsigned short* wih0t = g2t   + 512 * 512;             // [1536,512] rows g|i|o
  unsigned short* wcat3 = wih0t + (size_t)1536 * 512;    // [2048,1536] fused L1 B
  unsigned short* wch0ot= wcat3 + (size_t)2048 * 1536;   // [512,512]
  unsigned short* wch1ot= wch0ot + 512 * 512;            // [512,512]
  unsigned short* wend  = wch1ot + 512 * 512;
  unsigned short *a16, *tail16;                          // [CH,1024] = [hy0 | c]
  if (CH == 5000) {
    a16  = hbB16;
    tail16 = wend;
  } else {
    a16  = wend;
    tail16 = a16 + (size_t)CH * 1024;
  }
  float* stats = (float*)tail16;
  int*   csr   = (int*)(stats + 1024);
  int*   counts  = csr;
  int*   offsets = csr + 20032;
  int*   cpos    = csr + 40064;
  int*   s_s     = csr + 60096;
  float* w_s     = (float*)(csr + 380096);

  unsigned short* bufH16 = (unsigned short*)bufH;  // bf16 H during GCN
  float* cbuf = bufH;                              // CH*512 fp32 during LSTM
  float* obuf = bufH + (size_t)CH * HID;           // CH*512 fp32 (o-peephole)

  const dim3 blk(256);
  auto gemm128 = [&](const unsigned short* A, int lda,
                     const unsigned short* A2, int lda2, int ksplit,
                     const unsigned short* Bt, float* C, unsigned short* C16,
                     const float* bias, int M, int K, int Ksmall, int NC, int ldc,
                     int acc) {
    int nrowb = (M + 127) / 128;
    int ncolb = NC / 128;
    int nblocks = 8 * ((nrowb + 7) / 8) * ncolb;
    hipLaunchKernelGGL((gemm_bf16_k<128>), dim3(nblocks), blk, 0, stream,
                       A, lda, A2, lda2, ksplit, Bt, C, C16, bias,
                       M, K, Ksmall, NC, ldc, acc, nrowb, ncolb);
  };
  auto gemm64 = [&](const unsigned short* A, int lda,
                    const unsigned short* Bt, float* C, unsigned short* C16,
                    const float* bias, int M, int K, int NC, int ldc, int acc) {
    int nrowb = (M + 127) / 128;
    int ncolb = NC / 64;
    int nblocks = 8 * ((nrowb + 7) / 8) * ncolb;
    hipLaunchKernelGGL((gemm_bf16_k<64>), dim3(nblocks), blk, 0, stream,
                       A, lda, A, lda, K, Bt, C, C16, bias,
                       M, K, K, NC, ldc, acc, nrowb, ncolb);
  };
  auto tcvt = [&](const float* W, unsigned short* Wt, int K, int NC, int ldw, int ldo) {
    dim3 grid((NC + 31) / 32, (K + 31) / 32);
    hipLaunchKernelGGL(tcvt_k, grid, dim3(32, 8), 0, stream, W, Wt, K, NC, ldw, ldo);
  };
  auto zero = [&](float* p, size_t n) {
    hipLaunchKernelGGL(zero_k, dim3((unsigned)((n / 4 + 255) / 256)), blk, 0, stream, p, n);
  };

  // -------- weight prep --------
  const float* wih1 = wih + (size_t)HID * G4;
  const float* whh1 = whh + (size_t)HID * G4;
  const float* wch1 = wch + (size_t)HID * 3 * HID;
  tcvt(gcn0W, g0t, IN_CH, HID, HID, IN_CH);
  tcvt(gcnW,                     g1t, HID, HID, HID, HID);
  tcvt(gcnW + (size_t)HID * HID, g2t, HID, HID, HID, HID);
  // layer-0 Wih rows [g|i|o] (f dead: c=0); output cols G..O at ldc 2048
  tcvt(wih + 2 * HID, wih0t,                    HID, HID, G4, HID);  // g
  tcvt(wih,           wih0t + (size_t)512 * 512, HID, HID, G4, HID); // i
  tcvt(wih + 3 * HID, wih0t + (size_t)1024 * 512, HID, HID, G4, HID);// o
  // fused layer-1 B [2048 x 1536]: rows f,g K=1536 (ih|hh|peep); i,o K=1024
  tcvt(wih1 + HID,     wcat3 + (size_t)F_OFF * 1536,        HID, HID, G4, 1536);
  tcvt(whh1 + HID,     wcat3 + (size_t)F_OFF * 1536 + 512,  HID, HID, G4, 1536);
  tcvt(wch1 + HID,     wcat3 + (size_t)F_OFF * 1536 + 1024, HID, HID, 3 * HID, 1536);
  tcvt(wih1 + 2 * HID, wcat3 + (size_t)G_OFF * 1536,        HID, HID, G4, 1536);
  tcvt(whh1 + 2 * HID, wcat3 + (size_t)G_OFF * 1536 + 512,  HID, HID, G4, 1536);
  tcvt(wch1,           wcat3 + (size_t)G_OFF * 1536 + 1024, HID, HID, 3 * HID, 1536);
  tcvt(wih1,           wcat3 + (size_t)I_OFF * 1536,        HID, HID, G4, 1536);
  tcvt(whh1,           wcat3 + (size_t)I_OFF * 1536 + 512,  HID, HID, G4, 1536);
  tcvt(wih1 + 3 * HID, wcat3 + (size_t)O_OFF * 1536,        HID, HID, G4, 1536);
  tcvt(whh1 + 3 * HID, wcat3 + (size_t)O_OFF * 1536 + 512,  HID, HID, G4, 1536);
  tcvt(wch + 2 * HID,  wch0ot, HID, HID, 3 * HID, HID);   // Wch0 o-peephole
  tcvt(wch1 + 2 * HID, wch1ot, HID, HID, 3 * HID, HID);   // Wch1 o-peephole
  hipLaunchKernelGGL(cvt_k, dim3((N_NODES * IN_CH / 4 + 255) / 256), blk, 0, stream,
                     x, x16, (size_t)N_NODES * IN_CH);

  // -------- CSR build --------
  const int e_blocks = (N_EDGES + 255) / 256;
  zero((float*)counts, N_NODES);
  hipLaunchKernelGGL(hist_k, dim3(e_blocks), blk, 0, stream, dst, counts);
  hipLaunchKernelGGL(scan_k, dim3(1), dim3(1024), 0, stream, counts, offsets, cpos, N_NODES);
  hipLaunchKernelGGL(fill_k, dim3(e_blocks), blk, 0, stream, src, dst, ew, cpos, s_s, w_s);

  // -------- GCN layer 0: gather-first (linearity) --------
  hipLaunchKernelGGL(gather64_k, dim3(N_NODES / 4), dim3(64), 0, stream,
                     x16, offsets, s_s, w_s, hbB16);
  gemm64(hbB16, IN_CH, g0t, nullptr, bufH16, nullptr, N_NODES, IN_CH, HID, HID, 0);
  zero(stats, 2 * HID);
  hipLaunchKernelGGL(bn_stats_k, dim3(8, 64), blk, 0, stream, bufH16, stats, N_NODES);
  hipLaunchKernelGGL(bn_apply_k, dim3((unsigned)(NH / 4 / 256)), blk, 0, stream,
                     bufH16, stats, gamma, beta, hbA16, N_NODES);

  // -------- GCN layers 1,2: GEMM -> gather -> BN --------
  const unsigned short* gWt2[2] = {g1t, g2t};
  const unsigned short* gA2[2]  = {hbA16, hbB16};
  unsigned short*       gXW2[2] = {hbB16, hbA16};
  unsigned short*       gO2[2]  = {hbB16, hbA16};
  for (int l = 0; l < 2; l++) {
    gemm64(gA2[l], HID, gWt2[l], nullptr, gXW2[l], nullptr, N_NODES, HID, HID, HID, 0);
    hipLaunchKernelGGL(gather_k, dim3(N_NODES), dim3(128), 0, stream,
                       gXW2[l], offsets, s_s, w_s, bufH16);
    zero(stats, 2 * HID);
    hipLaunchKernelGGL(bn_stats_k, dim3(8, 64), blk, 0, stream, bufH16, stats, N_NODES);
    hipLaunchKernelGGL(bn_apply_k, dim3((unsigned)(NH / 4 / 256)), blk, 0, stream,
                       bufH16, stats, gamma + (l + 1) * HID, beta + (l + 1) * HID,
                       gO2[l], N_NODES);
  }
  unsigned short* hfin16 = hbA16;

  // -------- LSTM + output, chunked --------
  for (int ci = 0; ci < NCHUNK; ci++) {
    const int r0 = ci * CH;
    const unsigned short* h_c = hfin16 + (size_t)r0 * HID;
    const int cell_blocks = (int)(((size_t)CH * HID + 255) / 256);

    // layer 0 (h=c=0, f dead): gates[G|I|O] = h @ Wih0_gio
    gemm128(h_c, HID, h_c, HID, HID, wih0t, gates + G_OFF, nullptr, nullptr,
            CH, HID, HID, 1536, G4, 0);
    hipLaunchKernelGGL(cell1_k, dim3(cell_blocks), blk, 0, stream,
                       gates, lstmb, (const float*)nullptr, cbuf, a16 + 512, 1024, CH, 0);
    // o peephole L0 (fresh write): obuf = c0 @ Wch0_o
    gemm64(a16 + 512, 1024, wch0ot, obuf, nullptr, nullptr, CH, HID, HID, HID, 0);
    // hy0 -> a16[:,0:512] bf16
    hipLaunchKernelGGL(cell2_k, dim3(cell_blocks), blk, 0, stream,
                       gates, obuf, lstmb, cbuf, a16, 1024, CH);

    // layer 1 fused: gates = [h | hy0 | c0] @ wcat3 (split-A; f,g K=1536, i,o K=1024)
    gemm128(h_c, HID, a16, 1024, HID, wcat3, gates, nullptr, nullptr,
            CH, 1536, 1024, G4, G4, 0);
    hipLaunchKernelGGL(cell1_k, dim3(cell_blocks), blk, 0, stream,
                       gates, lstmb + G4, cbuf, cbuf, a16 + 512, 1024, CH, 1);
    // o peephole L1 (fresh write): obuf = c1 @ Wch1_o
    gemm64(a16 + 512, 1024, wch1ot, obuf, nullptr, nullptr, CH, HID, HID, HID, 0);
    // fused cell2 + output projection
    hipLaunchKernelGGL(cellout_k, dim3((CH * 64 + 255) / 256), blk, 0, stream,
                       gates, obuf, lstmb + G4, cbuf, outW, outb,
                       out + (size_t)r0 * 12, CH);
  }
}

// Round 14
// 968.708 us; speedup vs baseline: 1.4753x; 1.0492x over previous
//
#include <hip/hip_runtime.h>
#include <cstddef>

#define N_NODES 20000
#define N_EDGES 320000
#define IN_CH   64
#define HID     512
#define G4      2048
#define BN_EPS  1e-5f
// gate order in gates buffer: [f | g | i | o]
#define F_OFF   0
#define G_OFF   512
#define I_OFF   1024
#define O_OFF   1536

typedef __attribute__((ext_vector_type(8))) __bf16 bf16x8;
typedef __attribute__((ext_vector_type(4))) float f32x4;

__device__ __forceinline__ float sigmoidf_(float x) {
  return 1.0f / (1.0f + expf(-x));
}

// fp32 -> bf16 (RNE)
__device__ __forceinline__ unsigned short f2b(float f) {
  unsigned int u = __float_as_uint(f);
  u += 0x7FFFu + ((u >> 16) & 1u);
  return (unsigned short)(u >> 16);
}
__device__ __forceinline__ float b2f(unsigned short u) {
  return __uint_as_float(((unsigned int)u) << 16);
}

__device__ __forceinline__ void gld_lds16(const unsigned short* g, unsigned short* l) {
  __builtin_amdgcn_global_load_lds(
      (const __attribute__((address_space(1))) unsigned int*)(const void*)g,
      (__attribute__((address_space(3))) unsigned int*)(void*)l, 16, 0, 0);
}

// ---------------- zero fill ----------------
__global__ __launch_bounds__(256) void zero_k(float* __restrict__ p, size_t n) {
  size_t i = ((size_t)blockIdx.x * 256 + threadIdx.x) * 4;
  if (i + 3 < n) {
    *(float4*)&p[i] = make_float4(0.f, 0.f, 0.f, 0.f);
  } else {
    for (; i < n; i++) p[i] = 0.f;
  }
}

// ---------------- f32 -> bf16 ----------------
__global__ __launch_bounds__(256) void cvt_k(const float* __restrict__ in,
                                             unsigned short* __restrict__ out, size_t n) {
  size_t i = ((size_t)blockIdx.x * 256 + threadIdx.x) * 4;
  if (i + 3 < n) {
    const float4 v = *(const float4*)&in[i];
    ushort4 o; o.x = f2b(v.x); o.y = f2b(v.y); o.z = f2b(v.z); o.w = f2b(v.w);
    *(ushort4*)&out[i] = o;
  } else {
    for (; i < n; i++) out[i] = f2b(in[i]);
  }
}

// ---------------- transpose + cvt: Wt[n*ldo + k] = bf16(W[k*ldw + n]) ----------------
__global__ void tcvt_k(const float* __restrict__ W, unsigned short* __restrict__ Wt,
                       int K, int NC, int ldw, int ldo) {
  __shared__ float tile[32][33];
  const int n0 = blockIdx.x * 32, k0 = blockIdx.y * 32;
  const int tx = threadIdx.x, ty = threadIdx.y;  // 32 x 8
  #pragma unroll
  for (int i = 0; i < 32; i += 8) {
    int k = k0 + ty + i, n = n0 + tx;
    tile[ty + i][tx] = (k < K && n < NC) ? W[(size_t)k * ldw + n] : 0.f;
  }
  __syncthreads();
  #pragma unroll
  for (int i = 0; i < 32; i += 8) {
    int n = n0 + ty + i, k = k0 + tx;
    if (n < NC && k < K) Wt[(size_t)n * ldo + k] = f2b(tile[tx][ty + i]);
  }
}

// ---------------- CSR build ----------------
__global__ __launch_bounds__(256) void hist_k(const int* __restrict__ dst,
                                              int* __restrict__ counts) {
  int e = blockIdx.x * 256 + threadIdx.x;
  if (e < N_EDGES) atomicAdd(&counts[dst[e]], 1);
}

__global__ __launch_bounds__(1024) void scan_k(const int* __restrict__ counts,
                                               int* __restrict__ offsets,
                                               int* __restrict__ pos, int n) {
  __shared__ int tmp[1024];
  __shared__ int carry_s;
  const int tid = threadIdx.x;
  if (tid == 0) carry_s = 0;
  __syncthreads();
  for (int base = 0; base < n; base += 1024) {
    int i = base + tid;
    int v = (i < n) ? counts[i] : 0;
    tmp[tid] = v;
    __syncthreads();
    #pragma unroll
    for (int off = 1; off < 1024; off <<= 1) {
      int t = (tid >= off) ? tmp[tid - off] : 0;
      __syncthreads();
      tmp[tid] += t;
      __syncthreads();
    }
    if (i < n) {
      int excl = carry_s + tmp[tid] - v;
      offsets[i] = excl;
      pos[i] = excl;
    }
    __syncthreads();
    if (tid == 1023) carry_s += tmp[1023];
    __syncthreads();
  }
  if (tid == 0) offsets[n] = carry_s;
}

__global__ __launch_bounds__(256) void fill_k(
    const int* __restrict__ src, const int* __restrict__ dst,
    const float* __restrict__ ew, int* __restrict__ pos,
    int* __restrict__ s_s, float* __restrict__ w_s) {
  int e = blockIdx.x * 256 + threadIdx.x;
  if (e >= N_EDGES) return;
  int p = atomicAdd(&pos[dst[e]], 1);
  s_s[p] = src[e];
  w_s[p] = ew[e];
}

// ---------------- L0 gather on 64-col input: xg = S·x (linearity) ----------------
__global__ __launch_bounds__(64) void gather64_k(
    const unsigned short* __restrict__ x16, const int* __restrict__ offsets,
    const int* __restrict__ s_s, const float* __restrict__ w_s,
    unsigned short* __restrict__ xg) {
  const int sub = threadIdx.x >> 4;
  const int cg  = threadIdx.x & 15;
  const int n   = blockIdx.x * 4 + sub;
  const int beg = offsets[n], end = offsets[n + 1];
  float4 acc = make_float4(0.f, 0.f, 0.f, 0.f);
  for (int i = beg; i < end; i++) {
    const int   s = s_s[i];
    const float w = w_s[i];
    const ushort4 v = *(const ushort4*)&x16[(size_t)s * IN_CH + cg * 4];
    acc.x = fmaf(w, b2f(v.x), acc.x);
    acc.y = fmaf(w, b2f(v.y), acc.y);
    acc.z = fmaf(w, b2f(v.z), acc.z);
    acc.w = fmaf(w, b2f(v.w), acc.w);
  }
  ushort4 o; o.x = f2b(acc.x); o.y = f2b(acc.y); o.z = f2b(acc.z); o.w = f2b(acc.w);
  *(ushort4*)&xg[(size_t)n * IN_CH + cg * 4] = o;
}

// ---------------- aggregation gather (bf16 XW -> bf16 H) ----------------
__global__ __launch_bounds__(128) void gather_k(
    const unsigned short* __restrict__ XW, const int* __restrict__ offsets,
    const int* __restrict__ s_s, const float* __restrict__ w_s,
    unsigned short* __restrict__ H) {
  const int n = blockIdx.x;
  const int t = threadIdx.x;
  const int beg = offsets[n], end = offsets[n + 1];
  float4 acc = make_float4(0.f, 0.f, 0.f, 0.f);
  for (int i = beg; i < end; i++) {
    const int   s = s_s[i];
    const float w = w_s[i];
    const ushort4 v = *(const ushort4*)&XW[(size_t)s * HID + t * 4];
    acc.x = fmaf(w, b2f(v.x), acc.x);
    acc.y = fmaf(w, b2f(v.y), acc.y);
    acc.z = fmaf(w, b2f(v.z), acc.z);
    acc.w = fmaf(w, b2f(v.w), acc.w);
  }
  ushort4 o; o.x = f2b(acc.x); o.y = f2b(acc.y); o.z = f2b(acc.z); o.w = f2b(acc.w);
  *(ushort4*)&H[(size_t)n * HID + t * 4] = o;
}

// ---------------- BN stats over bf16 H ----------------
__global__ __launch_bounds__(256) void bn_stats_k(
    const unsigned short* __restrict__ H, float* __restrict__ stats, int N)
{
  const int tx = threadIdx.x & 63;
  const int ty = threadIdx.x >> 6;
  const int col = blockIdx.x * 64 + tx;
  float s1 = 0.f, s2 = 0.f;
  for (int r = blockIdx.y * 4 + ty; r < N; r += gridDim.y * 4) {
    float v = b2f(H[(size_t)r * HID + col]);
    s1 += v; s2 += v * v;
  }
  __shared__ float red[2][4][64];
  red[0][ty][tx] = s1;
  red[1][ty][tx] = s2;
  __syncthreads();
  if (ty == 0) {
    s1 = red[0][0][tx] + red[0][1][tx] + red[0][2][tx] + red[0][3][tx];
    s2 = red[1][0][tx] + red[1][1][tx] + red[1][2][tx] + red[1][3][tx];
    atomicAdd(&stats[col], s1);
    atomicAdd(&stats[HID + col], s2);
  }
}

// ---------------- BN apply + ReLU: bf16 H -> bf16 h ----------------
__global__ __launch_bounds__(256) void bn_apply_k(
    const unsigned short* __restrict__ H, const float* __restrict__ stats,
    const float* __restrict__ gamma, const float* __restrict__ beta,
    unsigned short* __restrict__ out, int N)
{
  size_t gid = (size_t)blockIdx.x * 256 + threadIdx.x;
  size_t idx = gid * 4;
  if (idx >= (size_t)N * HID) return;
  int col = (int)(idx & (HID - 1));
  const ushort4 v = *(const ushort4*)&H[idx];
  float r[4] = {b2f(v.x), b2f(v.y), b2f(v.z), b2f(v.w)};
  ushort4 o;
  unsigned short* op = &o.x;
  #pragma unroll
  for (int i = 0; i < 4; i++) {
    int c = col + i;
    float mean = stats[c] * (1.0f / N);
    float var  = stats[HID + c] * (1.0f / N) - mean * mean;
    float scale = gamma[c] / sqrtf(var + BN_EPS);
    float shift = beta[c] - mean * scale;
    op[i] = f2b(fmaxf(fmaf(r[i], scale, shift), 0.0f));
  }
  *(ushort4*)&out[idx] = o;
}

// ---------------- bf16 MFMA GEMM, BK=64, swizzled LDS + XCD mapping ----
// C(f32) or C16(bf16) [M,NC] (+)= A[M,K] * Bt[NC,K]^T (+bias)
// BK=64: half the barriers of BK=32; LDS row stride 128B with 8-slot chunk
// swizzle: row r's global 16B-chunk c stored at slot (c + r) & 7 -> fragment
// reads are 2-way bank aliasing (free). Split-A + variable-K as before.
template<int BN>
__global__ __launch_bounds__(256) void gemm_bf16_k(
    const unsigned short* __restrict__ A, int lda,
    const unsigned short* __restrict__ A2, int lda2, int ksplit,
    const unsigned short* __restrict__ Bt,
    float* __restrict__ C, unsigned short* __restrict__ C16,
    const float* __restrict__ bias,
    int M, int K, int Ksmall, int NC, int ldc, int acc, int nrowb, int ncolb)
{
  const int b   = blockIdx.x;
  const int xcd = b & 7;
  const int j   = b >> 3;
  const int col_b = j % ncolb;
  const int row_b = (j / ncolb) * 8 + xcd;
  if (row_b >= nrowb) return;

  constexpr int MI = (BN == 128) ? 4 : 2;
  __shared__ unsigned short As[128 * 64];
  __shared__ unsigned short Bs[BN * 64];
  const int row0 = row_b * 128;
  const int col0 = col_b * BN;
  const int Kthis = (col0 < 1024) ? K : Ksmall;
  const int t    = threadIdx.x;
  const int lane = t & 63;
  const int w    = t >> 6;
  const int wro  = (BN == 128) ? (w >> 1) * 64 : w * 32;
  const int wco  = (BN == 128) ? (w & 1) * 64 : 0;
  const int q    = lane >> 4;
  const int l16  = lane & 15;

  f32x4 accr[MI][4] = {};

  for (int k0 = 0; k0 < Kthis; k0 += 64) {
    // A staging: 128 rows x 8 chunks = 1024 slots; slot s = (r<<3)|cq holds
    // global chunk kq = (cq - r) & 7 of row r.
    #pragma unroll
    for (int i = 0; i < 4; i++) {
      int s  = t + i * 256;
      int r  = s >> 3, cq = s & 7;
      int kq = (cq - r) & 7;
      int gr = row0 + r; if (gr > M - 1) gr = M - 1;
      int kk = k0 + kq * 8;
      const unsigned short* bp = (kk < ksplit) ? A : A2;
      size_t off = (kk < ksplit) ? ((size_t)gr * lda + kk)
                                 : ((size_t)gr * lda2 + (kk - ksplit));
      gld_lds16(bp + off, As + (size_t)s * 8);
    }
    #pragma unroll
    for (int i = 0; i < BN / 32; i++) {
      int s  = t + i * 256;
      int r  = s >> 3, cq = s & 7;
      int kq = (cq - r) & 7;
      gld_lds16(Bt + (size_t)(col0 + r) * K + k0 + kq * 8, Bs + (size_t)s * 8);
    }
    __syncthreads();

    // two MFMA K-steps (ks = 0, 32) per LDS tile
    #pragma unroll
    for (int ks = 0; ks < 2; ks++) {
      bf16x8 af[MI], bf[4];
      #pragma unroll
      for (int mi = 0; mi < MI; mi++) {
        int r = wro + mi * 16 + l16;
        int slot = (ks * 4 + q + r) & 7;
        af[mi] = *(const bf16x8*)&As[r * 64 + slot * 8];
      }
      #pragma unroll
      for (int ni = 0; ni < 4; ni++) {
        int r = wco + ni * 16 + l16;
        int slot = (ks * 4 + q + r) & 7;
        bf[ni] = *(const bf16x8*)&Bs[r * 64 + slot * 8];
      }
      #pragma unroll
      for (int mi = 0; mi < MI; mi++)
        #pragma unroll
        for (int ni = 0; ni < 4; ni++)
          accr[mi][ni] = __builtin_amdgcn_mfma_f32_16x16x32_bf16(
              af[mi], bf[ni], accr[mi][ni], 0, 0, 0);
    }
    __syncthreads();
  }

  #pragma unroll
  for (int mi = 0; mi < MI; mi++) {
    #pragma unroll
    for (int ni = 0; ni < 4; ni++) {
      int col = col0 + wco + ni * 16 + l16;
      #pragma unroll
      for (int r = 0; r < 4; r++) {
        int row = row0 + wro + mi * 16 + q * 4 + r;
        if (row < M) {
          float v = accr[mi][ni][r];
          if (C16) {
            C16[(size_t)row * ldc + col] = f2b(v);
          } else {
            float* cp = &C[(size_t)row * ldc + col];
            if (acc)       *cp += v;
            else if (bias) *cp  = v + bias[col];
            else           *cp  = v;
          }
        }
      }
    }
  }
}

// ---------------- LSTM cell part 1 (gate order f|g|i|o; bias added here) --------
__global__ __launch_bounds__(256) void cell1_k(
    const float* __restrict__ gates, const float* __restrict__ lb,
    const float* __restrict__ cin,
    float* __restrict__ cout, unsigned short* __restrict__ cout16, int ld16,
    int rows, int hasC)
{
  size_t gid = (size_t)blockIdx.x * 256 + threadIdx.x;
  if (gid >= (size_t)rows * HID) return;
  size_t row = gid >> 9;
  int    col = (int)(gid & (HID - 1));
  const float* g = &gates[row * G4];
  float ig = sigmoidf_(g[I_OFF + col] + lb[col]);
  float gg = tanhf(g[G_OFF + col] + lb[2 * HID + col]);
  float c;
  if (hasC) {
    float fg = sigmoidf_(g[F_OFF + col] + lb[HID + col]);
    c = fg * cin[gid] + ig * gg;
  } else {
    c = ig * gg;
  }
  cout[gid] = c;
  cout16[row * ld16 + col] = f2b(c);
}

// ---------------- LSTM cell part 2: hy16 = sigma(gates_O + obuf + b_o)*tanh(c) ---
__global__ __launch_bounds__(256) void cell2_k(
    const float* __restrict__ gates, const float* __restrict__ obuf,
    const float* __restrict__ lb, const float* __restrict__ cy,
    unsigned short* __restrict__ hy16, int ld16, int rows)
{
  size_t gid = (size_t)blockIdx.x * 256 + threadIdx.x;
  if (gid >= (size_t)rows * HID) return;
  size_t row = gid >> 9;
  int    col = (int)(gid & (HID - 1));
  float og = sigmoidf_(gates[row * G4 + O_OFF + col] + obuf[gid] + lb[3 * HID + col]);
  float h = og * tanhf(cy[gid]);
  hy16[row * ld16 + col] = f2b(h);
}

// ---------------- fused final cell2 + output projection ----------------
__global__ __launch_bounds__(256) void cellout_k(
    const float* __restrict__ gates, const float* __restrict__ obuf,
    const float* __restrict__ lb, const float* __restrict__ cy,
    const float* __restrict__ W, const float* __restrict__ b,
    float* __restrict__ out, int rows)
{
  int wave = (int)(((size_t)blockIdx.x * 256 + threadIdx.x) >> 6);
  int lane = threadIdx.x & 63;
  if (wave >= rows) return;
  const float* g  = &gates[(size_t)wave * G4 + O_OFF];
  const float* ob = &obuf[(size_t)wave * HID];
  const float* cr = &cy[(size_t)wave * HID];
  float hy[8];
  #pragma unroll
  for (int j = 0; j < 8; j++) {
    int k = lane + j * 64;
    float og = sigmoidf_(g[k] + ob[k] + lb[3 * HID + k]);
    hy[j] = og * tanhf(cr[k]);
  }
  float acc[12] = {};
  #pragma unroll
  for (int j = 0; j < 8; j++) {
    int k = lane + j * 64;
    const float* wr = &W[k * 12];
    #pragma unroll
    for (int p = 0; p < 12; p++) acc[p] = fmaf(hy[j], wr[p], acc[p]);
  }
  #pragma unroll
  for (int p = 0; p < 12; p++) {
    float v = acc[p];
    #pragma unroll
    for (int off = 32; off > 0; off >>= 1) v += __shfl_down(v, off);
    if (lane == 0) out[(size_t)wave * 12 + p] = v + b[p];
  }
}

extern "C" void kernel_launch(void* const* d_in, const int* in_sizes, int n_in,
                              void* d_out, int out_size, void* d_ws, size_t ws_size,
                              hipStream_t stream) {
  const float* x     = (const float*)d_in[0];
  const int*   ei    = (const int*)d_in[1];
  const float* ew    = (const float*)d_in[2];
  const float* gcn0W = (const float*)d_in[3];
  const float* gcnW  = (const float*)d_in[5];
  const float* gamma = (const float*)d_in[7];
  const float* beta  = (const float*)d_in[8];
  const float* wih   = (const float*)d_in[9];
  const float* whh   = (const float*)d_in[10];
  const float* wch   = (const float*)d_in[11];
  const float* lstmb = (const float*)d_in[12];
  const float* outW  = (const float*)d_in[13];
  const float* outb  = (const float*)d_in[14];
  float* out = (float*)d_out;

  const int* src = ei;
  const int* dst = ei + N_EDGES;

  const int CH = (ws_size >= (size_t)215000000) ? 10000 : 5000;
  const int NCHUNK = N_NODES / CH;

  // -------- workspace layout --------
  const size_t NH = (size_t)N_NODES * HID;
  float* ws = (float*)d_ws;
  float* gates = ws;                                 // CH*2048 fp32
  float* bufH  = gates + (size_t)CH * G4;            // NH fp32 (bf16 H / cbuf+obuf)
  unsigned short* hbA16 = (unsigned short*)(bufH + NH);
  unsigned short* hbB16 = hbA16 + NH;
  unsigned short* x16   = hbB16 + NH;
  unsigned short* g0t   = x16 + (size_t)N_NODES * IN_CH;
  unsigned short* g1t   = g0t   + 512 * 64;
  unsigned short* g2t   = g1t   + 512 * 512;
  unsigned short* wih0t = g2t   + 512 * 512;             // [1536,512] rows g|i|o
  unsigned short* wcat3 = wih0t + (size_t)1536 * 512;    // [2048,1536] fused L1 B
  unsigned short* wch0ot= wcat3 + (size_t)2048 * 1536;   // [512,512]
  unsigned short* wch1ot= wch0ot + 512 * 512;            // [512,512]
  unsigned short* wend  = wch1ot + 512 * 512;
  unsigned short *a16, *tail16;                          // [CH,1024] = [hy0 | c]
  if (CH == 5000) {
    a16  = hbB16;
    tail16 = wend;
  } else {
    a16  = wend;
    tail16 = a16 + (size_t)CH * 1024;
  }
  float* stats = (float*)tail16;
  int*   csr   = (int*)(stats + 1024);
  int*   counts  = csr;
  int*   offsets = csr + 20032;
  int*   cpos    = csr + 40064;
  int*   s_s     = csr + 60096;
  float* w_s     = (float*)(csr + 380096);

  unsigned short* bufH16 = (unsigned short*)bufH;  // bf16 H during GCN
  float* cbuf = bufH;                              // CH*512 fp32 during LSTM
  float* obuf = bufH + (size_t)CH * HID;           // CH*512 fp32 (o-peephole)

  const dim3 blk(256);
  auto gemm128 = [&](const unsigned short* A, int lda,
                     const unsigned short* A2, int lda2, int ksplit,
                     const unsigned short* Bt, float* C, unsigned short* C16,
                     const float* bias, int M, int K, int Ksmall, int NC, int ldc,
                     int acc) {
    int nrowb = (M + 127) / 128;
    int ncolb = NC / 128;
    int nblocks = 8 * ((nrowb + 7) / 8) * ncolb;
    hipLaunchKernelGGL((gemm_bf16_k<128>), dim3(nblocks), blk, 0, stream,
                       A, lda, A2, lda2, ksplit, Bt, C, C16, bias,
                       M, K, Ksmall, NC, ldc, acc, nrowb, ncolb);
  };
  auto gemm64 = [&](const unsigned short* A, int lda,
                    const unsigned short* Bt, float* C, unsigned short* C16,
                    const float* bias, int M, int K, int NC, int ldc, int acc) {
    int nrowb = (M + 127) / 128;
    int ncolb = NC / 64;
    int nblocks = 8 * ((nrowb + 7) / 8) * ncolb;
    hipLaunchKernelGGL((gemm_bf16_k<64>), dim3(nblocks), blk, 0, stream,
                       A, lda, A, lda, K, Bt, C, C16, bias,
                       M, K, K, NC, ldc, acc, nrowb, ncolb);
  };
  auto tcvt = [&](const float* W, unsigned short* Wt, int K, int NC, int ldw, int ldo) {
    dim3 grid((NC + 31) / 32, (K + 31) / 32);
    hipLaunchKernelGGL(tcvt_k, grid, dim3(32, 8), 0, stream, W, Wt, K, NC, ldw, ldo);
  };
  auto zero = [&](float* p, size_t n) {
    hipLaunchKernelGGL(zero_k, dim3((unsigned)((n / 4 + 255) / 256)), blk, 0, stream, p, n);
  };

  // -------- weight prep --------
  const float* wih1 = wih + (size_t)HID * G4;
  const float* whh1 = whh + (size_t)HID * G4;
  const float* wch1 = wch + (size_t)HID * 3 * HID;
  tcvt(gcn0W, g0t, IN_CH, HID, HID, IN_CH);
  tcvt(gcnW,                     g1t, HID, HID, HID, HID);
  tcvt(gcnW + (size_t)HID * HID, g2t, HID, HID, HID, HID);
  // layer-0 Wih rows [g|i|o] (f dead: c=0)
  tcvt(wih + 2 * HID, wih0t,                      HID, HID, G4, HID);  // g
  tcvt(wih,           wih0t + (size_t)512 * 512,  HID, HID, G4, HID);  // i
  tcvt(wih + 3 * HID, wih0t + (size_t)1024 * 512, HID, HID, G4, HID);  // o
  // fused layer-1 B [2048 x 1536]: rows f,g K=1536 (ih|hh|peep); i,o K=1024
  tcvt(wih1 + HID,     wcat3 + (size_t)F_OFF * 1536,        HID, HID, G4, 1536);
  tcvt(whh1 + HID,     wcat3 + (size_t)F_OFF * 1536 + 512,  HID, HID, G4, 1536);
  tcvt(wch1 + HID,     wcat3 + (size_t)F_OFF * 1536 + 1024, HID, HID, 3 * HID, 1536);
  tcvt(wih1 + 2 * HID, wcat3 + (size_t)G_OFF * 1536,        HID, HID, G4, 1536);
  tcvt(whh1 + 2 * HID, wcat3 + (size_t)G_OFF * 1536 + 512,  HID, HID, G4, 1536);
  tcvt(wch1,           wcat3 + (size_t)G_OFF * 1536 + 1024, HID, HID, 3 * HID, 1536);
  tcvt(wih1,           wcat3 + (size_t)I_OFF * 1536,        HID, HID, G4, 1536);
  tcvt(whh1,           wcat3 + (size_t)I_OFF * 1536 + 512,  HID, HID, G4, 1536);
  tcvt(wih1 + 3 * HID, wcat3 + (size_t)O_OFF * 1536,        HID, HID, G4, 1536);
  tcvt(whh1 + 3 * HID, wcat3 + (size_t)O_OFF * 1536 + 512,  HID, HID, G4, 1536);
  tcvt(wch + 2 * HID,  wch0ot, HID, HID, 3 * HID, HID);   // Wch0 o-peephole
  tcvt(wch1 + 2 * HID, wch1ot, HID, HID, 3 * HID, HID);   // Wch1 o-peephole
  hipLaunchKernelGGL(cvt_k, dim3((N_NODES * IN_CH / 4 + 255) / 256), blk, 0, stream,
                     x, x16, (size_t)N_NODES * IN_CH);

  // -------- CSR build --------
  const int e_blocks = (N_EDGES + 255) / 256;
  zero((float*)counts, N_NODES);
  hipLaunchKernelGGL(hist_k, dim3(e_blocks), blk, 0, stream, dst, counts);
  hipLaunchKernelGGL(scan_k, dim3(1), dim3(1024), 0, stream, counts, offsets, cpos, N_NODES);
  hipLaunchKernelGGL(fill_k, dim3(e_blocks), blk, 0, stream, src, dst, ew, cpos, s_s, w_s);

  // -------- GCN layer 0: gather-first (linearity) --------
  hipLaunchKernelGGL(gather64_k, dim3(N_NODES / 4), dim3(64), 0, stream,
                     x16, offsets, s_s, w_s, hbB16);
  gemm64(hbB16, IN_CH, g0t, nullptr, bufH16, nullptr, N_NODES, IN_CH, HID, HID, 0);
  zero(stats, 2 * HID);
  hipLaunchKernelGGL(bn_stats_k, dim3(8, 64), blk, 0, stream, bufH16, stats, N_NODES);
  hipLaunchKernelGGL(bn_apply_k, dim3((unsigned)(NH / 4 / 256)), blk, 0, stream,
                     bufH16, stats, gamma, beta, hbA16, N_NODES);

  // -------- GCN layers 1,2: GEMM -> gather -> BN --------
  const unsigned short* gWt2[2] = {g1t, g2t};
  const unsigned short* gA2[2]  = {hbA16, hbB16};
  unsigned short*       gXW2[2] = {hbB16, hbA16};
  unsigned short*       gO2[2]  = {hbB16, hbA16};
  for (int l = 0; l < 2; l++) {
    gemm64(gA2[l], HID, gWt2[l], nullptr, gXW2[l], nullptr, N_NODES, HID, HID, HID, 0);
    hipLaunchKernelGGL(gather_k, dim3(N_NODES), dim3(128), 0, stream,
                       gXW2[l], offsets, s_s, w_s, bufH16);
    zero(stats, 2 * HID);
    hipLaunchKernelGGL(bn_stats_k, dim3(8, 64), blk, 0, stream, bufH16, stats, N_NODES);
    hipLaunchKernelGGL(bn_apply_k, dim3((unsigned)(NH / 4 / 256)), blk, 0, stream,
                       bufH16, stats, gamma + (l + 1) * HID, beta + (l + 1) * HID,
                       gO2[l], N_NODES);
  }
  unsigned short* hfin16 = hbA16;

  // -------- LSTM + output, chunked --------
  for (int ci = 0; ci < NCHUNK; ci++) {
    const int r0 = ci * CH;
    const unsigned short* h_c = hfin16 + (size_t)r0 * HID;
    const int cell_blocks = (int)(((size_t)CH * HID + 255) / 256);

    // layer 0 (h=c=0, f dead): gates[G|I|O] = h @ Wih0_gio
    gemm128(h_c, HID, h_c, HID, HID, wih0t, gates + G_OFF, nullptr, nullptr,
            CH, HID, HID, 1536, G4, 0);
    hipLaunchKernelGGL(cell1_k, dim3(cell_blocks), blk, 0, stream,
                       gates, lstmb, (const float*)nullptr, cbuf, a16 + 512, 1024, CH, 0);
    // o peephole L0 (fresh write): obuf = c0 @ Wch0_o
    gemm64(a16 + 512, 1024, wch0ot, obuf, nullptr, nullptr, CH, HID, HID, HID, 0);
    // hy0 -> a16[:,0:512] bf16
    hipLaunchKernelGGL(cell2_k, dim3(cell_blocks), blk, 0, stream,
                       gates, obuf, lstmb, cbuf, a16, 1024, CH);

    // layer 1 fused: gates = [h | hy0 | c0] @ wcat3 (split-A; f,g K=1536, i,o K=1024)
    gemm128(h_c, HID, a16, 1024, HID, wcat3, gates, nullptr, nullptr,
            CH, 1536, 1024, G4, G4, 0);
    hipLaunchKernelGGL(cell1_k, dim3(cell_blocks), blk, 0, stream,
                       gates, lstmb + G4, cbuf, cbuf, a16 + 512, 1024, CH, 1);
    // o peephole L1 (fresh write): obuf = c1 @ Wch1_o
    gemm64(a16 + 512, 1024, wch1ot, obuf, nullptr, nullptr, CH, HID, HID, HID, 0);
    // fused cell2 + output projection
    hipLaunchKernelGGL(cellout_k, dim3((CH * 64 + 255) / 256), blk, 0, stream,
                       gates, obuf, lstmb + G4, cbuf, outW, outb,
                       out + (size_t)r0 * 12, CH);
  }
}